// Round 1
// baseline (3216.485 us; speedup 1.0000x reference)
//
#include <hip/hip_runtime.h>
#include <math.h>

// Problem constants (match reference)
constexpr int N_NODES = 65536;
constexpr int N_EDGES = 2097152;
constexpr int F_IN    = 128;
constexpr int H_DIM   = 256;
constexpr int O_DIM   = 128;
constexpr int N_GRAPH = 256;

// ---------------- degree / norm ----------------

__global__ void k_deg_init(float* __restrict__ deg) {
    int i = blockIdx.x * blockDim.x + threadIdx.x;
    if (i < N_NODES) deg[i] = 1.0f;   // self-loop weight 1
}

__global__ void k_deg_edge(const int* __restrict__ col, const float* __restrict__ ew,
                           float* __restrict__ deg) {
    int e = blockIdx.x * blockDim.x + threadIdx.x;
    if (e < N_EDGES) atomicAdd(&deg[col[e]], ew[e]);
}

__global__ void k_dis(float* __restrict__ deg) {
    int i = blockIdx.x * blockDim.x + threadIdx.x;
    if (i < N_NODES) {
        float d = deg[i];
        deg[i] = (d > 0.0f) ? 1.0f / sqrtf(fmaxf(d, 1e-30f)) : 0.0f;
    }
}

// ---------------- GEMM1: gather(chord_feats) @ W1 -> xw1 [N,256] ----------------
// block: 256 threads, 8 nodes per block. x rows staged in LDS (broadcast reads),
// W1[k*256+h] coalesced across threads.

__global__ void k_gemm1(const float* __restrict__ cf, const int* __restrict__ nidx,
                        const float* __restrict__ W1, float* __restrict__ xw1) {
    __shared__ float xs[8 * F_IN];
    int nb = blockIdx.x * 8;
    int t  = threadIdx.x;
    #pragma unroll
    for (int p = 0; p < 4; ++p) {
        int j = p * 2 + (t >> 7);
        int k = t & 127;
        int r = nidx[nb + j];
        xs[j * F_IN + k] = cf[r * F_IN + k];
    }
    __syncthreads();
    float acc[8] = {0.f, 0.f, 0.f, 0.f, 0.f, 0.f, 0.f, 0.f};
    int h = t;
    for (int k = 0; k < F_IN; ++k) {
        float w = W1[k * H_DIM + h];
        #pragma unroll
        for (int j = 0; j < 8; ++j) acc[j] += xs[j * F_IN + k] * w;
    }
    #pragma unroll
    for (int j = 0; j < 8; ++j) xw1[(nb + j) * H_DIM + h] = acc[j];
}

// ---------------- agg init: b + self-loop term ----------------

__global__ void k_init1(const float* __restrict__ xw1, const float* __restrict__ dis,
                        const float* __restrict__ b1, float* __restrict__ agg1) {
    int i = blockIdx.x;
    int h = threadIdx.x;
    float d = dis[i];
    agg1[i * H_DIM + h] = b1[h] + xw1[i * H_DIM + h] * d * d;
}

__global__ void k_init2(const float* __restrict__ xw2, const float* __restrict__ dis,
                        const float* __restrict__ b2, float* __restrict__ agg2) {
    int i = blockIdx.x;
    int o = threadIdx.x;
    float d = dis[i];
    agg2[i * O_DIM + o] = b2[o] + xw2[i * O_DIM + o] * d * d;
}

// ---------------- edge scatter (atomics) ----------------

__global__ void k_edge1(const int* __restrict__ row, const int* __restrict__ col,
                        const float* __restrict__ ew, const float* __restrict__ dis,
                        const float* __restrict__ xw1, float* __restrict__ agg1) {
    int e = blockIdx.x;
    int r = row[e], c = col[e];
    float nrm = dis[r] * ew[e] * dis[c];
    int h = threadIdx.x;
    atomicAdd(&agg1[c * H_DIM + h], xw1[r * H_DIM + h] * nrm);
}

__global__ void k_edge2(const int* __restrict__ row, const int* __restrict__ col,
                        const float* __restrict__ ew, const float* __restrict__ dis,
                        const float* __restrict__ xw2, float* __restrict__ agg2) {
    int e = blockIdx.x * 2 + (threadIdx.x >> 7);
    int o = threadIdx.x & 127;
    int r = row[e], c = col[e];
    float nrm = dis[r] * ew[e] * dis[c];
    atomicAdd(&agg2[c * O_DIM + o], xw2[r * O_DIM + o] * nrm);
}

// ---------------- GEMM2: relu(agg1) @ W2 -> xw2 [N,128] ----------------
// block: 256 threads, 8 nodes per block; each thread computes 4 outputs.

__global__ void k_gemm2(const float* __restrict__ agg1, const float* __restrict__ W2,
                        float* __restrict__ xw2) {
    __shared__ float xs[8 * H_DIM];
    int nb = blockIdx.x * 8;
    int t  = threadIdx.x;
    #pragma unroll
    for (int p = 0; p < 8; ++p) {
        int j = p;
        int k = t;
        float v = agg1[(nb + j) * H_DIM + k];
        xs[j * H_DIM + k] = v > 0.0f ? v : 0.0f;
    }
    __syncthreads();
    int o  = t & 127;
    int jg = t >> 7;       // 0 or 1 -> node group of 4
    float acc[4] = {0.f, 0.f, 0.f, 0.f};
    for (int k = 0; k < H_DIM; ++k) {
        float w = W2[k * O_DIM + o];
        #pragma unroll
        for (int j = 0; j < 4; ++j) acc[j] += xs[(jg * 4 + j) * H_DIM + k] * w;
    }
    #pragma unroll
    for (int j = 0; j < 4; ++j) xw2[(nb + jg * 4 + j) * O_DIM + o] = acc[j];
}

// ---------------- pooling ----------------

__global__ void k_zero_pool(float* __restrict__ pool) {
    int i = blockIdx.x * blockDim.x + threadIdx.x;
    if (i < N_GRAPH * O_DIM + N_GRAPH) pool[i] = 0.0f;
}

__global__ void k_pool(const float* __restrict__ agg2, const int* __restrict__ batch,
                       float* __restrict__ pool, float* __restrict__ cnt) {
    int i = blockIdx.x;
    int o = threadIdx.x;
    float v = agg2[i * O_DIM + o];
    v = v > 0.0f ? v : 0.0f;
    int b = batch[i];
    atomicAdd(&pool[b * O_DIM + o], v);
    if (o == 0) atomicAdd(&cnt[b], 1.0f);
}

__global__ void k_final(const float* __restrict__ pool, const float* __restrict__ cnt,
                        float* __restrict__ out) {
    int t = blockIdx.x * blockDim.x + threadIdx.x;
    if (t < N_GRAPH * O_DIM) {
        int g = t / O_DIM;
        out[t] = pool[t] / fmaxf(cnt[g], 1.0f);
    }
}

// ---------------- launch ----------------

extern "C" void kernel_launch(void* const* d_in, const int* in_sizes, int n_in,
                              void* d_out, int out_size, void* d_ws, size_t ws_size,
                              hipStream_t stream) {
    const float* cf   = (const float*)d_in[0];   // [V,128]
    const float* W1   = (const float*)d_in[1];   // [128,256]
    const float* b1   = (const float*)d_in[2];   // [256]
    const float* W2   = (const float*)d_in[3];   // [256,128]
    const float* b2   = (const float*)d_in[4];   // [128]
    const float* ew   = (const float*)d_in[5];   // [E]
    const int*   nidx = (const int*)d_in[6];     // [N]
    const int*   eidx = (const int*)d_in[7];     // [2,E]
    const int*   bidx = (const int*)d_in[8];     // [N]
    float* out = (float*)d_out;

    const int* row = eidx;            // source
    const int* col = eidx + N_EDGES;  // target

    // workspace layout
    char* ws = (char*)d_ws;
    float* dis  = (float*)ws;                                   // N floats (deg then dis)
    float* bufA = (float*)(ws + (size_t)262144);                // N*256 floats (xw1; later xw2+agg2)
    float* bufB = (float*)(ws + (size_t)262144 + (size_t)N_NODES * H_DIM * 4); // N*256 floats (agg1)
    float* pool = (float*)(ws + (size_t)262144 + (size_t)2 * N_NODES * H_DIM * 4);
    float* cnt  = pool + N_GRAPH * O_DIM;

    float* xw1  = bufA;
    float* agg1 = bufB;
    float* xw2  = bufA;                        // reuse (xw1 dead after edge1)
    float* agg2 = bufA + (size_t)N_NODES * O_DIM;

    // 1. degree & norm
    k_deg_init<<<N_NODES / 256, 256, 0, stream>>>(dis);
    k_deg_edge<<<N_EDGES / 256, 256, 0, stream>>>(col, ew, dis);
    k_dis<<<N_NODES / 256, 256, 0, stream>>>(dis);

    // 2. layer 1
    k_gemm1<<<N_NODES / 8, 256, 0, stream>>>(cf, nidx, W1, xw1);
    k_init1<<<N_NODES, 256, 0, stream>>>(xw1, dis, b1, agg1);
    k_edge1<<<N_EDGES, 256, 0, stream>>>(row, col, ew, dis, xw1, agg1);

    // 3. layer 2
    k_gemm2<<<N_NODES / 8, 256, 0, stream>>>(agg1, W2, xw2);
    k_init2<<<N_NODES, 128, 0, stream>>>(xw2, dis, b2, agg2);
    k_edge2<<<N_EDGES / 2, 256, 0, stream>>>(row, col, ew, dis, xw2, agg2);

    // 4. mean pool
    k_zero_pool<<<(N_GRAPH * O_DIM + N_GRAPH + 255) / 256, 256, 0, stream>>>(pool);
    k_pool<<<N_NODES, 128, 0, stream>>>(agg2, bidx, pool, cnt);
    k_final<<<(N_GRAPH * O_DIM + 255) / 256, 256, 0, stream>>>(pool, cnt, out);
}

// Round 2
// 1125.787 us; speedup vs baseline: 2.8571x; 2.8571x over previous
//
#include <hip/hip_runtime.h>
#include <math.h>

// Problem constants (match reference)
constexpr int N_NODES = 65536;
constexpr int N_EDGES = 2097152;
constexpr int F_IN    = 128;
constexpr int H_DIM   = 256;
constexpr int O_DIM   = 128;
constexpr int N_GRAPH = 256;

// ---------------- degree / norm ----------------

__global__ void k_deg_init(float* __restrict__ deg) {
    int i = blockIdx.x * blockDim.x + threadIdx.x;
    deg[i] = 1.0f;   // self-loop weight 1
}

__global__ void k_deg_edge(const int* __restrict__ col, const float* __restrict__ ew,
                           float* __restrict__ deg) {
    int e = blockIdx.x * blockDim.x + threadIdx.x;
    atomicAdd(&deg[col[e]], ew[e]);
}

__global__ void k_dis(float* __restrict__ deg) {
    int i = blockIdx.x * blockDim.x + threadIdx.x;
    float d = deg[i];
    deg[i] = (d > 0.0f) ? 1.0f / sqrtf(fmaxf(d, 1e-30f)) : 0.0f;
}

// ---------------- CSR build: count / scan / scatter ----------------

__global__ void k_zero_int(int* __restrict__ p) {
    p[blockIdx.x * blockDim.x + threadIdx.x] = 0;
}

__global__ void k_count(const int* __restrict__ col, int* __restrict__ cnt) {
    int e = blockIdx.x * blockDim.x + threadIdx.x;
    atomicAdd(&cnt[col[e]], 1);
}

__global__ void k_scan1(const int* __restrict__ cnt, int* __restrict__ offs,
                        int* __restrict__ bsum) {
    __shared__ int s[256];
    int tid = threadIdx.x;
    int i = blockIdx.x * 256 + tid;
    int v = cnt[i];
    s[tid] = v;
    __syncthreads();
    for (int d = 1; d < 256; d <<= 1) {
        int t = (tid >= d) ? s[tid - d] : 0;
        __syncthreads();
        s[tid] += t;
        __syncthreads();
    }
    offs[i] = s[tid] - v;                 // exclusive within block
    if (tid == 255) bsum[blockIdx.x] = s[255];
}

__global__ void k_scan2(int* __restrict__ bsum) {
    __shared__ int s[256];
    int tid = threadIdx.x;
    int v = bsum[tid];
    s[tid] = v;
    __syncthreads();
    for (int d = 1; d < 256; d <<= 1) {
        int t = (tid >= d) ? s[tid - d] : 0;
        __syncthreads();
        s[tid] += t;
        __syncthreads();
    }
    bsum[tid] = s[tid] - v;               // exclusive block offsets
}

__global__ void k_scan3(int* __restrict__ offs, const int* __restrict__ bsum,
                        int* __restrict__ cursor) {
    int i = blockIdx.x * 256 + threadIdx.x;
    int o = offs[i] + bsum[blockIdx.x];
    offs[i] = o;
    cursor[i] = o;
    if (i == 0) offs[N_NODES] = N_EDGES;
}

__global__ void k_scatter(const int* __restrict__ row, const int* __restrict__ col,
                          const float* __restrict__ ew, const float* __restrict__ dis,
                          int* __restrict__ cursor,
                          int* __restrict__ csr_src, float* __restrict__ csr_nrm) {
    int e = blockIdx.x * blockDim.x + threadIdx.x;
    int r = row[e], c = col[e];
    float nrm = dis[r] * ew[e] * dis[c];
    int slot = atomicAdd(&cursor[c], 1);
    csr_src[slot] = r;
    csr_nrm[slot] = nrm;
}

// ---------------- layer-1 pre-aggregation on raw 128-dim features ----------------
// aggX[c] = dis[c]^2 * cf[nidx[c]] + sum_in-edges nrm * cf[nidx[src]]

__global__ void k_agg0(const float* __restrict__ cf, const int* __restrict__ nidx,
                       const float* __restrict__ dis,
                       const int* __restrict__ offs, const int* __restrict__ csr_src,
                       const float* __restrict__ csr_nrm, float* __restrict__ aggX) {
    int c = blockIdx.x;
    int f = threadIdx.x;
    float d = dis[c];
    float acc = cf[(size_t)nidx[c] * F_IN + f] * d * d;
    int s0 = offs[c], s1 = offs[c + 1];
    for (int s = s0; s < s1; ++s) {
        int r = csr_src[s];
        float nm = csr_nrm[s];
        acc += cf[(size_t)nidx[r] * F_IN + f] * nm;
    }
    aggX[(size_t)c * F_IN + f] = acc;
}

// ---------------- GEMM1: aggX [N,128] @ W1 [128,256] + b1, relu -> h1 [N,256] ----

__global__ void k_gemm1(const float* __restrict__ aggX, const float* __restrict__ W1,
                        const float* __restrict__ b1, float* __restrict__ h1) {
    __shared__ float xs[8 * F_IN];
    int nb = blockIdx.x * 8;
    int t  = threadIdx.x;
    #pragma unroll
    for (int p = 0; p < 4; ++p) {
        int idx = p * 256 + t;
        int j = idx >> 7, k = idx & 127;
        xs[idx] = aggX[(size_t)(nb + j) * F_IN + k];
    }
    __syncthreads();
    float acc[8] = {0.f, 0.f, 0.f, 0.f, 0.f, 0.f, 0.f, 0.f};
    int h = t;
    for (int k = 0; k < F_IN; ++k) {
        float w = W1[k * H_DIM + h];
        #pragma unroll
        for (int j = 0; j < 8; ++j) acc[j] += xs[j * F_IN + k] * w;
    }
    float bb = b1[h];
    #pragma unroll
    for (int j = 0; j < 8; ++j) {
        float v = acc[j] + bb;
        h1[(size_t)(nb + j) * H_DIM + h] = v > 0.0f ? v : 0.0f;
    }
}

// ---------------- GEMM2: h1 [N,256] @ W2 [256,128] -> xw2 [N,128] ----------------

__global__ void k_gemm2(const float* __restrict__ h1, const float* __restrict__ W2,
                        float* __restrict__ xw2) {
    __shared__ float xs[8 * H_DIM];
    int nb = blockIdx.x * 8;
    int t  = threadIdx.x;
    #pragma unroll
    for (int p = 0; p < 8; ++p) {
        int idx = p * 256 + t;
        int j = idx >> 8, k = idx & 255;
        xs[idx] = h1[(size_t)(nb + j) * H_DIM + k];
    }
    __syncthreads();
    int o  = t & 127;
    int jg = t >> 7;
    float acc[4] = {0.f, 0.f, 0.f, 0.f};
    for (int k = 0; k < H_DIM; ++k) {
        float w = W2[k * O_DIM + o];
        #pragma unroll
        for (int j = 0; j < 4; ++j) acc[j] += xs[(jg * 4 + j) * H_DIM + k] * w;
    }
    #pragma unroll
    for (int j = 0; j < 4; ++j) xw2[(size_t)(nb + jg * 4 + j) * O_DIM + o] = acc[j];
}

// ---------------- layer-2 aggregation + relu + fused mean-pool scatter ----------

__global__ void k_zero_pool(float* __restrict__ pool) {
    int i = blockIdx.x * blockDim.x + threadIdx.x;
    if (i < N_GRAPH * O_DIM + N_GRAPH) pool[i] = 0.0f;
}

__global__ void k_agg2_pool(const float* __restrict__ xw2, const float* __restrict__ b2,
                            const float* __restrict__ dis,
                            const int* __restrict__ offs, const int* __restrict__ csr_src,
                            const float* __restrict__ csr_nrm,
                            const int* __restrict__ batch, float* __restrict__ pool) {
    int c = blockIdx.x;
    int o = threadIdx.x;
    float d = dis[c];
    float acc = b2[o] + xw2[(size_t)c * O_DIM + o] * d * d;
    int s0 = offs[c], s1 = offs[c + 1];
    for (int s = s0; s < s1; ++s) {
        int r = csr_src[s];
        float nm = csr_nrm[s];
        acc += xw2[(size_t)r * O_DIM + o] * nm;
    }
    acc = acc > 0.0f ? acc : 0.0f;
    atomicAdd(&pool[batch[c] * O_DIM + o], acc);
}

__global__ void k_cnt(const int* __restrict__ batch, float* __restrict__ cnt) {
    int i = blockIdx.x * blockDim.x + threadIdx.x;
    atomicAdd(&cnt[batch[i]], 1.0f);
}

__global__ void k_final(const float* __restrict__ pool, const float* __restrict__ cnt,
                        float* __restrict__ out) {
    int t = blockIdx.x * blockDim.x + threadIdx.x;
    if (t < N_GRAPH * O_DIM) {
        int g = t / O_DIM;
        out[t] = pool[t] / fmaxf(cnt[g], 1.0f);
    }
}

// ---------------- launch ----------------

extern "C" void kernel_launch(void* const* d_in, const int* in_sizes, int n_in,
                              void* d_out, int out_size, void* d_ws, size_t ws_size,
                              hipStream_t stream) {
    const float* cf   = (const float*)d_in[0];   // [V,128]
    const float* W1   = (const float*)d_in[1];   // [128,256]
    const float* b1   = (const float*)d_in[2];   // [256]
    const float* W2   = (const float*)d_in[3];   // [256,128]
    const float* b2   = (const float*)d_in[4];   // [128]
    const float* ew   = (const float*)d_in[5];   // [E]
    const int*   nidx = (const int*)d_in[6];     // [N]
    const int*   eidx = (const int*)d_in[7];     // [2,E]
    const int*   bidx = (const int*)d_in[8];     // [N]
    float* out = (float*)d_out;

    const int* row = eidx;            // source
    const int* col = eidx + N_EDGES;  // target

    // workspace layout (bytes)
    char* ws = (char*)d_ws;
    size_t off = 0;
    float* dis    = (float*)(ws + off); off += (size_t)N_NODES * 4;        // 256K
    int*   cnt_i  = (int*)  (ws + off); off += (size_t)N_NODES * 4;        // 256K
    int*   offs   = (int*)  (ws + off); off += (size_t)(N_NODES + 16) * 4; // 256K+
    int*   cursor = (int*)  (ws + off); off += (size_t)N_NODES * 4;        // 256K
    int*   bsum   = (int*)  (ws + off); off += 4096;
    int*   csr_src= (int*)  (ws + off); off += (size_t)N_EDGES * 4;        // 8M
    float* csr_nrm= (float*)(ws + off); off += (size_t)N_EDGES * 4;        // 8M
    float* pool   = (float*)(ws + off); off += (size_t)(N_GRAPH * O_DIM + N_GRAPH) * 4;
    off = (off + 255) & ~(size_t)255;
    float* aggX   = (float*)(ws + off);                                    // N*128 (32M), later xw2
    float* h1     = (float*)(ws + off + (size_t)N_NODES * F_IN * 4);       // N*256 (64M)
    float* xw2    = aggX;   // aggX dead after GEMM1
    float* cntf   = pool + N_GRAPH * O_DIM;

    // 1. degree & norm
    k_deg_init<<<N_NODES / 256, 256, 0, stream>>>(dis);
    k_deg_edge<<<N_EDGES / 256, 256, 0, stream>>>(col, ew, dis);
    k_dis<<<N_NODES / 256, 256, 0, stream>>>(dis);

    // 2. CSR build
    k_zero_int<<<N_NODES / 256, 256, 0, stream>>>(cnt_i);
    k_count<<<N_EDGES / 256, 256, 0, stream>>>(col, cnt_i);
    k_scan1<<<256, 256, 0, stream>>>(cnt_i, offs, bsum);
    k_scan2<<<1, 256, 0, stream>>>(bsum);
    k_scan3<<<256, 256, 0, stream>>>(offs, bsum, cursor);
    k_scatter<<<N_EDGES / 256, 256, 0, stream>>>(row, col, ew, dis, cursor, csr_src, csr_nrm);

    // 3. layer 1: aggregate raw features, then GEMM (+b1, relu)
    k_agg0<<<N_NODES, 128, 0, stream>>>(cf, nidx, dis, offs, csr_src, csr_nrm, aggX);
    k_gemm1<<<N_NODES / 8, 256, 0, stream>>>(aggX, W1, b1, h1);

    // 4. layer 2: GEMM then aggregate (+b2, relu) fused with pool scatter
    k_gemm2<<<N_NODES / 8, 256, 0, stream>>>(h1, W2, xw2);
    k_zero_pool<<<(N_GRAPH * O_DIM + N_GRAPH + 255) / 256, 256, 0, stream>>>(pool);
    k_agg2_pool<<<N_NODES, 128, 0, stream>>>(xw2, b2, dis, offs, csr_src, csr_nrm, bidx, pool);

    // 5. counts + final divide
    k_cnt<<<N_NODES / 256, 256, 0, stream>>>(bidx, cntf);
    k_final<<<(N_GRAPH * O_DIM + 255) / 256, 256, 0, stream>>>(pool, cntf, out);
}

// Round 3
// 889.421 us; speedup vs baseline: 3.6164x; 1.2658x over previous
//
#include <hip/hip_runtime.h>
#include <hip/hip_fp16.h>
#include <math.h>

// Problem constants (match reference)
constexpr int N_NODES = 65536;
constexpr int N_EDGES = 2097152;
constexpr int F_IN    = 128;
constexpr int H_DIM   = 256;
constexpr int O_DIM   = 128;
constexpr int N_GRAPH = 256;
constexpr int V_SIZE  = 1000;

// ---------------- init: deg=1 (self-loop), cnt=0 ----------------

__global__ void k_init(float* __restrict__ deg, int* __restrict__ cnt) {
    int i = blockIdx.x * blockDim.x + threadIdx.x;
    deg[i] = 1.0f;
    cnt[i] = 0;
}

// ---------------- cf -> fp16 table ----------------

__global__ void k_cvt_cf(const float* __restrict__ cf, __half* __restrict__ cf16) {
    int i = blockIdx.x * blockDim.x + threadIdx.x;   // V*F_IN = 128000
    cf16[i] = __float2half(cf[i]);
}

// ---------------- fused degree + count (one edge pass) ----------------

__global__ void k_deg_count(const int* __restrict__ col, const float* __restrict__ ew,
                            float* __restrict__ deg, int* __restrict__ cnt) {
    int e = blockIdx.x * blockDim.x + threadIdx.x;
    int c = col[e];
    atomicAdd(&deg[c], ew[e]);
    atomicAdd(&cnt[c], 1);
}

__global__ void k_dis(float* __restrict__ deg) {
    int i = blockIdx.x * blockDim.x + threadIdx.x;
    float d = deg[i];
    deg[i] = (d > 0.0f) ? 1.0f / sqrtf(fmaxf(d, 1e-30f)) : 0.0f;
}

// ---------------- CSR scan ----------------

__global__ void k_scan1(const int* __restrict__ cnt, int* __restrict__ offs,
                        int* __restrict__ bsum) {
    __shared__ int s[256];
    int tid = threadIdx.x;
    int i = blockIdx.x * 256 + tid;
    int v = cnt[i];
    s[tid] = v;
    __syncthreads();
    for (int d = 1; d < 256; d <<= 1) {
        int t = (tid >= d) ? s[tid - d] : 0;
        __syncthreads();
        s[tid] += t;
        __syncthreads();
    }
    offs[i] = s[tid] - v;
    if (tid == 255) bsum[blockIdx.x] = s[255];
}

__global__ void k_scan2(int* __restrict__ bsum) {
    __shared__ int s[256];
    int tid = threadIdx.x;
    int v = bsum[tid];
    s[tid] = v;
    __syncthreads();
    for (int d = 1; d < 256; d <<= 1) {
        int t = (tid >= d) ? s[tid - d] : 0;
        __syncthreads();
        s[tid] += t;
        __syncthreads();
    }
    bsum[tid] = s[tid] - v;
}

__global__ void k_scan3(int* __restrict__ offs, const int* __restrict__ bsum,
                        int* __restrict__ cursor) {
    int i = blockIdx.x * 256 + threadIdx.x;
    int o = offs[i] + bsum[blockIdx.x];
    offs[i] = o;
    cursor[i] = o;
    if (i == 0) offs[N_NODES] = N_EDGES;
}

// ---------------- scatter: packed (src<<10 | vocab, nrm) int2 ----------------

__global__ void k_scatter(const int* __restrict__ row, const int* __restrict__ col,
                          const float* __restrict__ ew, const float* __restrict__ dis,
                          const int* __restrict__ nidx, int* __restrict__ cursor,
                          int2* __restrict__ csr) {
    int e = blockIdx.x * blockDim.x + threadIdx.x;
    int r = row[e], c = col[e];
    float nrm = dis[r] * ew[e] * dis[c];
    int packed = (r << 10) | nidx[r];
    int slot = atomicAdd(&cursor[c], 1);
    int2 ent; ent.x = packed; ent.y = __float_as_int(nrm);
    csr[slot] = ent;
}

// ---------------- layer-1 aggregation of fp16 cf rows (wave per node) --------

__global__ void k_agg0(const __half2* __restrict__ cf16, const int* __restrict__ nidx,
                       const float* __restrict__ dis, const int* __restrict__ offs,
                       const int2* __restrict__ csr, float2* __restrict__ aggX) {
    int wave = threadIdx.x >> 6;
    int lane = threadIdx.x & 63;
    int c = blockIdx.x * 4 + wave;
    float d = dis[c];
    float2 self = __half22float2(cf16[(size_t)nidx[c] * 64 + lane]);
    float dd = d * d;
    float2 acc;
    acc.x = self.x * dd;
    acc.y = self.y * dd;
    int s0 = offs[c], s1 = offs[c + 1];
    int s = s0;
    for (; s + 2 <= s1; s += 2) {
        int2 e0 = csr[s], e1 = csr[s + 1];
        float2 v0 = __half22float2(cf16[(size_t)(e0.x & 1023) * 64 + lane]);
        float2 v1 = __half22float2(cf16[(size_t)(e1.x & 1023) * 64 + lane]);
        float n0 = __int_as_float(e0.y), n1 = __int_as_float(e1.y);
        acc.x += v0.x * n0; acc.y += v0.y * n0;
        acc.x += v1.x * n1; acc.y += v1.y * n1;
    }
    if (s < s1) {
        int2 e0 = csr[s];
        float2 v0 = __half22float2(cf16[(size_t)(e0.x & 1023) * 64 + lane]);
        float n0 = __int_as_float(e0.y);
        acc.x += v0.x * n0; acc.y += v0.y * n0;
    }
    aggX[(size_t)c * 64 + lane] = acc;
}

// ---------------- GEMM1: aggX [N,128] @ W1 + b1, relu -> h1 [N,256] ----------

__global__ void k_gemm1(const float* __restrict__ aggX, const float* __restrict__ W1,
                        const float* __restrict__ b1, float* __restrict__ h1) {
    __shared__ float xs[8 * F_IN];
    int nb = blockIdx.x * 8;
    int t  = threadIdx.x;
    #pragma unroll
    for (int p = 0; p < 4; ++p) {
        int idx = p * 256 + t;
        int j = idx >> 7, k = idx & 127;
        xs[idx] = aggX[(size_t)(nb + j) * F_IN + k];
    }
    __syncthreads();
    float acc[8] = {0.f, 0.f, 0.f, 0.f, 0.f, 0.f, 0.f, 0.f};
    int h = t;
    for (int k = 0; k < F_IN; ++k) {
        float w = W1[k * H_DIM + h];
        #pragma unroll
        for (int j = 0; j < 8; ++j) acc[j] += xs[j * F_IN + k] * w;
    }
    float bb = b1[h];
    #pragma unroll
    for (int j = 0; j < 8; ++j) {
        float v = acc[j] + bb;
        h1[(size_t)(nb + j) * H_DIM + h] = v > 0.0f ? v : 0.0f;
    }
}

// ---------------- GEMM2: h1 [N,256] @ W2 -> xw2 (fp16) [N,128] ---------------

__global__ void k_gemm2(const float* __restrict__ h1, const float* __restrict__ W2,
                        __half* __restrict__ xw2h) {
    __shared__ float xs[8 * H_DIM];
    int nb = blockIdx.x * 8;
    int t  = threadIdx.x;
    #pragma unroll
    for (int p = 0; p < 8; ++p) {
        int idx = p * 256 + t;
        int j = idx >> 8, k = idx & 255;
        xs[idx] = h1[(size_t)(nb + j) * H_DIM + k];
    }
    __syncthreads();
    int o  = t & 127;
    int jg = t >> 7;
    float acc[4] = {0.f, 0.f, 0.f, 0.f};
    for (int k = 0; k < H_DIM; ++k) {
        float w = W2[k * O_DIM + o];
        #pragma unroll
        for (int j = 0; j < 4; ++j) acc[j] += xs[(jg * 4 + j) * H_DIM + k] * w;
    }
    #pragma unroll
    for (int j = 0; j < 4; ++j)
        xw2h[(size_t)(nb + jg * 4 + j) * O_DIM + o] = __float2half(acc[j]);
}

// ---------------- layer-2 aggregation + relu + pool (wave per node) ----------

__global__ void k_zero_pool(float* __restrict__ pool) {
    int i = blockIdx.x * blockDim.x + threadIdx.x;
    if (i < N_GRAPH * O_DIM + N_GRAPH) pool[i] = 0.0f;
}

__global__ void k_agg2_pool(const __half2* __restrict__ xw2h, const float* __restrict__ b2,
                            const float* __restrict__ dis, const int* __restrict__ offs,
                            const int2* __restrict__ csr, const int* __restrict__ batch,
                            float* __restrict__ pool) {
    int wave = threadIdx.x >> 6;
    int lane = threadIdx.x & 63;
    int c = blockIdx.x * 4 + wave;
    float d = dis[c];
    float2 self = __half22float2(xw2h[(size_t)c * 64 + lane]);
    float2 bb = ((const float2*)b2)[lane];
    float dd = d * d;
    float2 acc;
    acc.x = bb.x + self.x * dd;
    acc.y = bb.y + self.y * dd;
    int s0 = offs[c], s1 = offs[c + 1];
    int s = s0;
    for (; s + 2 <= s1; s += 2) {
        int2 e0 = csr[s], e1 = csr[s + 1];
        float2 v0 = __half22float2(xw2h[(size_t)(e0.x >> 10) * 64 + lane]);
        float2 v1 = __half22float2(xw2h[(size_t)(e1.x >> 10) * 64 + lane]);
        float n0 = __int_as_float(e0.y), n1 = __int_as_float(e1.y);
        acc.x += v0.x * n0; acc.y += v0.y * n0;
        acc.x += v1.x * n1; acc.y += v1.y * n1;
    }
    if (s < s1) {
        int2 e0 = csr[s];
        float2 v0 = __half22float2(xw2h[(size_t)(e0.x >> 10) * 64 + lane]);
        float n0 = __int_as_float(e0.y);
        acc.x += v0.x * n0; acc.y += v0.y * n0;
    }
    acc.x = acc.x > 0.0f ? acc.x : 0.0f;
    acc.y = acc.y > 0.0f ? acc.y : 0.0f;
    int g = batch[c];
    atomicAdd(&pool[g * O_DIM + 2 * lane], acc.x);
    atomicAdd(&pool[g * O_DIM + 2 * lane + 1], acc.y);
}

__global__ void k_cnt(const int* __restrict__ batch, float* __restrict__ cnt) {
    int i = blockIdx.x * blockDim.x + threadIdx.x;
    atomicAdd(&cnt[batch[i]], 1.0f);
}

__global__ void k_final(const float* __restrict__ pool, const float* __restrict__ cnt,
                        float* __restrict__ out) {
    int t = blockIdx.x * blockDim.x + threadIdx.x;
    if (t < N_GRAPH * O_DIM) {
        int g = t / O_DIM;
        out[t] = pool[t] / fmaxf(cnt[g], 1.0f);
    }
}

// ---------------- launch ----------------

extern "C" void kernel_launch(void* const* d_in, const int* in_sizes, int n_in,
                              void* d_out, int out_size, void* d_ws, size_t ws_size,
                              hipStream_t stream) {
    const float* cf   = (const float*)d_in[0];   // [V,128]
    const float* W1   = (const float*)d_in[1];   // [128,256]
    const float* b1   = (const float*)d_in[2];   // [256]
    const float* W2   = (const float*)d_in[3];   // [256,128]
    const float* b2   = (const float*)d_in[4];   // [128]
    const float* ew   = (const float*)d_in[5];   // [E]
    const int*   nidx = (const int*)d_in[6];     // [N]
    const int*   eidx = (const int*)d_in[7];     // [2,E]
    const int*   bidx = (const int*)d_in[8];     // [N]
    float* out = (float*)d_out;

    const int* row = eidx;            // source
    const int* col = eidx + N_EDGES;  // target

    // workspace layout (bytes)
    char* ws = (char*)d_ws;
    size_t off = 0;
    float* dis    = (float*)(ws + off); off += (size_t)N_NODES * 4;
    int*   cnt_i  = (int*)  (ws + off); off += (size_t)N_NODES * 4;
    int*   offs   = (int*)  (ws + off); off += (size_t)(N_NODES + 16) * 4;
    int*   cursor = (int*)  (ws + off); off += (size_t)N_NODES * 4;
    int*   bsum   = (int*)  (ws + off); off += 4096;
    int2*  csr    = (int2*) (ws + off); off += (size_t)N_EDGES * 8;       // 16M
    float* pool   = (float*)(ws + off); off += (size_t)(N_GRAPH * O_DIM + N_GRAPH) * 4;
    __half* cf16  = (__half*)(ws + off); off += (size_t)V_SIZE * F_IN * 2; // 256K
    off = (off + 255) & ~(size_t)255;
    float* aggX   = (float*)(ws + off); off += (size_t)N_NODES * F_IN * 4; // 32M (xw2h reuses)
    float* h1     = (float*)(ws + off);                                    // 64M
    __half* xw2h  = (__half*)aggX;   // aggX dead after gemm1
    float* cntf   = pool + N_GRAPH * O_DIM;

    // 1. init + fp16 table + degree/count (one edge pass)
    k_init<<<N_NODES / 256, 256, 0, stream>>>(dis, cnt_i);
    k_cvt_cf<<<V_SIZE * F_IN / 256, 256, 0, stream>>>(cf, cf16);
    k_deg_count<<<N_EDGES / 256, 256, 0, stream>>>(col, ew, dis, cnt_i);
    k_dis<<<N_NODES / 256, 256, 0, stream>>>(dis);

    // 2. CSR build
    k_scan1<<<256, 256, 0, stream>>>(cnt_i, offs, bsum);
    k_scan2<<<1, 256, 0, stream>>>(bsum);
    k_scan3<<<256, 256, 0, stream>>>(offs, bsum, cursor);
    k_scatter<<<N_EDGES / 256, 256, 0, stream>>>(row, col, ew, dis, nidx, cursor, csr);

    // 3. layer 1: aggregate fp16 features (wave/node), then GEMM (+b1, relu)
    k_agg0<<<N_NODES / 4, 256, 0, stream>>>((const __half2*)cf16, nidx, dis, offs, csr,
                                            (float2*)aggX);
    k_gemm1<<<N_NODES / 8, 256, 0, stream>>>(aggX, W1, b1, h1);

    // 4. layer 2: GEMM -> fp16, aggregate + relu + pool scatter
    k_gemm2<<<N_NODES / 8, 256, 0, stream>>>(h1, W2, xw2h);
    k_zero_pool<<<(N_GRAPH * O_DIM + N_GRAPH + 255) / 256, 256, 0, stream>>>(pool);
    k_agg2_pool<<<N_NODES / 4, 256, 0, stream>>>((const __half2*)xw2h, b2, dis, offs, csr,
                                                 bidx, pool);

    // 5. counts + final divide
    k_cnt<<<N_NODES / 256, 256, 0, stream>>>(bidx, cntf);
    k_final<<<(N_GRAPH * O_DIM + 255) / 256, 256, 0, stream>>>(pool, cntf, out);
}

// Round 5
// 790.847 us; speedup vs baseline: 4.0671x; 1.1246x over previous
//
#include <hip/hip_runtime.h>
#include <hip/hip_fp16.h>
#include <math.h>

// Problem constants (match reference)
constexpr int N_NODES = 65536;
constexpr int N_EDGES = 2097152;
constexpr int F_IN    = 128;
constexpr int H_DIM   = 256;
constexpr int O_DIM   = 128;
constexpr int N_GRAPH = 256;
constexpr int V_SIZE  = 1000;

// ---------------- init: deg=1, cnt=0, pool=0, cf16 convert (full coverage) ---

__global__ void k_init(float* __restrict__ deg, int* __restrict__ cnt,
                       float* __restrict__ pool, const float* __restrict__ cf,
                       __half* __restrict__ cf16) {
    int i = blockIdx.x * blockDim.x + threadIdx.x;
    deg[i] = 1.0f;
    cnt[i] = 0;
    if (i < N_GRAPH * O_DIM + N_GRAPH) pool[i] = 0.0f;
    // V_SIZE*F_IN = 128000 > 65536 threads: convert 2 elements per thread
    if (i < V_SIZE * F_IN) cf16[i] = __float2half(cf[i]);
    int i2 = i + N_NODES;
    if (i2 < V_SIZE * F_IN) cf16[i2] = __float2half(cf[i2]);
}

// ---------------- fused degree + count (one edge pass) ----------------

__global__ void k_deg_count(const int* __restrict__ col, const float* __restrict__ ew,
                            float* __restrict__ deg, int* __restrict__ cnt) {
    int e = blockIdx.x * blockDim.x + threadIdx.x;
    int c = col[e];
    atomicAdd(&deg[c], ew[e]);
    atomicAdd(&cnt[c], 1);
}

// ---------------- dis + batch counts ----------------

__global__ void k_dis(float* __restrict__ deg, const int* __restrict__ batch,
                      float* __restrict__ cntf) {
    int i = blockIdx.x * blockDim.x + threadIdx.x;
    float d = deg[i];
    deg[i] = (d > 0.0f) ? 1.0f / sqrtf(fmaxf(d, 1e-30f)) : 0.0f;
    atomicAdd(&cntf[batch[i]], 1.0f);
}

// ---------------- CSR scan ----------------

__global__ void k_scan1(const int* __restrict__ cnt, int* __restrict__ offs,
                        int* __restrict__ bsum) {
    __shared__ int s[256];
    int tid = threadIdx.x;
    int i = blockIdx.x * 256 + tid;
    int v = cnt[i];
    s[tid] = v;
    __syncthreads();
    for (int d = 1; d < 256; d <<= 1) {
        int t = (tid >= d) ? s[tid - d] : 0;
        __syncthreads();
        s[tid] += t;
        __syncthreads();
    }
    offs[i] = s[tid] - v;
    if (tid == 255) bsum[blockIdx.x] = s[255];
}

__global__ void k_scan2(int* __restrict__ bsum) {
    __shared__ int s[256];
    int tid = threadIdx.x;
    int v = bsum[tid];
    s[tid] = v;
    __syncthreads();
    for (int d = 1; d < 256; d <<= 1) {
        int t = (tid >= d) ? s[tid - d] : 0;
        __syncthreads();
        s[tid] += t;
        __syncthreads();
    }
    bsum[tid] = s[tid] - v;
}

__global__ void k_scan3(int* __restrict__ offs, const int* __restrict__ bsum,
                        int* __restrict__ cursor) {
    int i = blockIdx.x * 256 + threadIdx.x;
    int o = offs[i] + bsum[blockIdx.x];
    offs[i] = o;
    cursor[i] = o;
    if (i == 0) offs[N_NODES] = N_EDGES;
}

// ---------------- scatter: packed (src<<10 | vocab, nrm) int2 ----------------

__global__ void k_scatter(const int* __restrict__ row, const int* __restrict__ col,
                          const float* __restrict__ ew, const float* __restrict__ dis,
                          const int* __restrict__ nidx, int* __restrict__ cursor,
                          int2* __restrict__ csr) {
    int e = blockIdx.x * blockDim.x + threadIdx.x;
    int r = row[e], c = col[e];
    float nrm = dis[r] * ew[e] * dis[c];
    int packed = (r << 10) | nidx[r];
    int slot = atomicAdd(&cursor[c], 1);
    int2 ent; ent.x = packed; ent.y = __float_as_int(nrm);
    csr[slot] = ent;
}

// ---------------- layer-1 aggregation of fp16 cf rows (wave per node) --------

__global__ void k_agg0(const __half2* __restrict__ cf16, const int* __restrict__ nidx,
                       const float* __restrict__ dis, const int* __restrict__ offs,
                       const int2* __restrict__ csr, float2* __restrict__ aggX) {
    int wave = threadIdx.x >> 6;
    int lane = threadIdx.x & 63;
    int c = blockIdx.x * 4 + wave;
    float d = dis[c];
    float2 self = __half22float2(cf16[(size_t)nidx[c] * 64 + lane]);
    float dd = d * d;
    float2 acc;
    acc.x = self.x * dd;
    acc.y = self.y * dd;
    int s0 = offs[c], s1 = offs[c + 1];
    int s = s0;
    for (; s + 4 <= s1; s += 4) {
        int2 e0 = csr[s], e1 = csr[s + 1], e2 = csr[s + 2], e3 = csr[s + 3];
        float2 v0 = __half22float2(cf16[(size_t)(e0.x & 1023) * 64 + lane]);
        float2 v1 = __half22float2(cf16[(size_t)(e1.x & 1023) * 64 + lane]);
        float2 v2 = __half22float2(cf16[(size_t)(e2.x & 1023) * 64 + lane]);
        float2 v3 = __half22float2(cf16[(size_t)(e3.x & 1023) * 64 + lane]);
        float n0 = __int_as_float(e0.y), n1 = __int_as_float(e1.y);
        float n2 = __int_as_float(e2.y), n3 = __int_as_float(e3.y);
        acc.x += v0.x * n0; acc.y += v0.y * n0;
        acc.x += v1.x * n1; acc.y += v1.y * n1;
        acc.x += v2.x * n2; acc.y += v2.y * n2;
        acc.x += v3.x * n3; acc.y += v3.y * n3;
    }
    for (; s < s1; ++s) {
        int2 e0 = csr[s];
        float2 v0 = __half22float2(cf16[(size_t)(e0.x & 1023) * 64 + lane]);
        float n0 = __int_as_float(e0.y);
        acc.x += v0.x * n0; acc.y += v0.y * n0;
    }
    aggX[(size_t)c * 64 + lane] = acc;
}

// ---------------- GEMM1: aggX [N,128] @ W1 + b1, relu -> h1 [N,256] ----------
// 32-node tile; thread = 8 nodes x 4 h-cols; LDS reads are wave-uniform.

__global__ void k_gemm1(const float* __restrict__ aggX, const float* __restrict__ W1,
                        const float* __restrict__ b1, float* __restrict__ h1) {
    __shared__ float xs[32 * F_IN];   // 16 KB
    int nb = blockIdx.x * 32;
    int t  = threadIdx.x;
    const float4* src = (const float4*)(aggX + (size_t)nb * F_IN);
    float4* dst = (float4*)xs;
    #pragma unroll
    for (int p = 0; p < 4; ++p) dst[p * 256 + t] = src[p * 256 + t];
    __syncthreads();
    int o  = t & 63;
    int jg = t >> 6;
    const float* xsj = xs + jg * 8 * F_IN;
    float acc[8][4] = {};
    for (int k = 0; k < F_IN; ++k) {
        float w0 = W1[k * H_DIM + o];
        float w1 = W1[k * H_DIM + o + 64];
        float w2 = W1[k * H_DIM + o + 128];
        float w3 = W1[k * H_DIM + o + 192];
        #pragma unroll
        for (int j = 0; j < 8; ++j) {
            float x = xsj[j * F_IN + k];
            acc[j][0] += x * w0; acc[j][1] += x * w1;
            acc[j][2] += x * w2; acc[j][3] += x * w3;
        }
    }
    float bb0 = b1[o], bb1 = b1[o + 64], bb2 = b1[o + 128], bb3 = b1[o + 192];
    #pragma unroll
    for (int j = 0; j < 8; ++j) {
        size_t base = (size_t)(nb + jg * 8 + j) * H_DIM + o;
        float v0 = acc[j][0] + bb0, v1 = acc[j][1] + bb1;
        float v2 = acc[j][2] + bb2, v3 = acc[j][3] + bb3;
        h1[base]       = v0 > 0.f ? v0 : 0.f;
        h1[base + 64]  = v1 > 0.f ? v1 : 0.f;
        h1[base + 128] = v2 > 0.f ? v2 : 0.f;
        h1[base + 192] = v3 > 0.f ? v3 : 0.f;
    }
}

// ---------------- GEMM2: h1 [N,256] @ W2 -> xw2 (fp16) [N,128] ---------------
// 32-node tile; thread = 8 nodes x 2 o-cols.

__global__ void k_gemm2(const float* __restrict__ h1, const float* __restrict__ W2,
                        __half* __restrict__ xw2h) {
    __shared__ float xs[32 * H_DIM];  // 32 KB
    int nb = blockIdx.x * 32;
    int t  = threadIdx.x;
    const float4* src = (const float4*)(h1 + (size_t)nb * H_DIM);
    float4* dst = (float4*)xs;
    #pragma unroll
    for (int p = 0; p < 8; ++p) dst[p * 256 + t] = src[p * 256 + t];
    __syncthreads();
    int o  = t & 63;
    int jg = t >> 6;
    const float* xsj = xs + jg * 8 * H_DIM;
    float acc[8][2] = {};
    for (int k = 0; k < H_DIM; ++k) {
        float w0 = W2[k * O_DIM + o];
        float w1 = W2[k * O_DIM + o + 64];
        #pragma unroll
        for (int j = 0; j < 8; ++j) {
            float x = xsj[j * H_DIM + k];
            acc[j][0] += x * w0; acc[j][1] += x * w1;
        }
    }
    #pragma unroll
    for (int j = 0; j < 8; ++j) {
        size_t base = (size_t)(nb + jg * 8 + j) * O_DIM + o;
        xw2h[base]      = __float2half(acc[j][0]);
        xw2h[base + 64] = __float2half(acc[j][1]);
    }
}

// ---------------- layer-2 aggregation + relu + pool (wave per node) ----------

__global__ void k_agg2_pool(const __half2* __restrict__ xw2h, const float* __restrict__ b2,
                            const float* __restrict__ dis, const int* __restrict__ offs,
                            const int2* __restrict__ csr, const int* __restrict__ batch,
                            float* __restrict__ pool) {
    int wave = threadIdx.x >> 6;
    int lane = threadIdx.x & 63;
    int c = blockIdx.x * 4 + wave;
    float d = dis[c];
    float2 self = __half22float2(xw2h[(size_t)c * 64 + lane]);
    float2 bb = ((const float2*)b2)[lane];
    float dd = d * d;
    float2 acc;
    acc.x = bb.x + self.x * dd;
    acc.y = bb.y + self.y * dd;
    int s0 = offs[c], s1 = offs[c + 1];
    int s = s0;
    for (; s + 4 <= s1; s += 4) {
        int2 e0 = csr[s], e1 = csr[s + 1], e2 = csr[s + 2], e3 = csr[s + 3];
        float2 v0 = __half22float2(xw2h[(size_t)(e0.x >> 10) * 64 + lane]);
        float2 v1 = __half22float2(xw2h[(size_t)(e1.x >> 10) * 64 + lane]);
        float2 v2 = __half22float2(xw2h[(size_t)(e2.x >> 10) * 64 + lane]);
        float2 v3 = __half22float2(xw2h[(size_t)(e3.x >> 10) * 64 + lane]);
        float n0 = __int_as_float(e0.y), n1 = __int_as_float(e1.y);
        float n2 = __int_as_float(e2.y), n3 = __int_as_float(e3.y);
        acc.x += v0.x * n0; acc.y += v0.y * n0;
        acc.x += v1.x * n1; acc.y += v1.y * n1;
        acc.x += v2.x * n2; acc.y += v2.y * n2;
        acc.x += v3.x * n3; acc.y += v3.y * n3;
    }
    for (; s < s1; ++s) {
        int2 e0 = csr[s];
        float2 v0 = __half22float2(xw2h[(size_t)(e0.x >> 10) * 64 + lane]);
        float n0 = __int_as_float(e0.y);
        acc.x += v0.x * n0; acc.y += v0.y * n0;
    }
    acc.x = acc.x > 0.0f ? acc.x : 0.0f;
    acc.y = acc.y > 0.0f ? acc.y : 0.0f;
    int g = batch[c];
    atomicAdd(&pool[g * O_DIM + 2 * lane], acc.x);
    atomicAdd(&pool[g * O_DIM + 2 * lane + 1], acc.y);
}

__global__ void k_final(const float* __restrict__ pool, const float* __restrict__ cnt,
                        float* __restrict__ out) {
    int t = blockIdx.x * blockDim.x + threadIdx.x;
    if (t < N_GRAPH * O_DIM) {
        int g = t / O_DIM;
        out[t] = pool[t] / fmaxf(cnt[g], 1.0f);
    }
}

// ---------------- launch ----------------

extern "C" void kernel_launch(void* const* d_in, const int* in_sizes, int n_in,
                              void* d_out, int out_size, void* d_ws, size_t ws_size,
                              hipStream_t stream) {
    const float* cf   = (const float*)d_in[0];   // [V,128]
    const float* W1   = (const float*)d_in[1];   // [128,256]
    const float* b1   = (const float*)d_in[2];   // [256]
    const float* W2   = (const float*)d_in[3];   // [256,128]
    const float* b2   = (const float*)d_in[4];   // [128]
    const float* ew   = (const float*)d_in[5];   // [E]
    const int*   nidx = (const int*)d_in[6];     // [N]
    const int*   eidx = (const int*)d_in[7];     // [2,E]
    const int*   bidx = (const int*)d_in[8];     // [N]
    float* out = (float*)d_out;

    const int* row = eidx;            // source
    const int* col = eidx + N_EDGES;  // target

    // workspace layout (bytes)
    char* ws = (char*)d_ws;
    size_t off = 0;
    float* dis    = (float*)(ws + off); off += (size_t)N_NODES * 4;
    int*   cnt_i  = (int*)  (ws + off); off += (size_t)N_NODES * 4;
    int*   offs   = (int*)  (ws + off); off += (size_t)(N_NODES + 16) * 4;
    int*   cursor = (int*)  (ws + off); off += (size_t)N_NODES * 4;
    int*   bsum   = (int*)  (ws + off); off += 4096;
    int2*  csr    = (int2*) (ws + off); off += (size_t)N_EDGES * 8;       // 16M
    float* pool   = (float*)(ws + off); off += (size_t)(N_GRAPH * O_DIM + N_GRAPH) * 4;
    __half* cf16  = (__half*)(ws + off); off += (size_t)V_SIZE * F_IN * 2; // 256K
    off = (off + 255) & ~(size_t)255;
    float* aggX   = (float*)(ws + off); off += (size_t)N_NODES * F_IN * 4; // 32M (xw2h reuses)
    float* h1     = (float*)(ws + off);                                    // 64M
    __half* xw2h  = (__half*)aggX;   // aggX dead after gemm1
    float* cntf   = pool + N_GRAPH * O_DIM;

    // 1. init (deg=1, cnt=0, pool=0, cf16 full table) + degree/count + dis/batch-count
    k_init<<<N_NODES / 256, 256, 0, stream>>>(dis, cnt_i, pool, cf, cf16);
    k_deg_count<<<N_EDGES / 256, 256, 0, stream>>>(col, ew, dis, cnt_i);
    k_dis<<<N_NODES / 256, 256, 0, stream>>>(dis, bidx, cntf);

    // 2. CSR build
    k_scan1<<<256, 256, 0, stream>>>(cnt_i, offs, bsum);
    k_scan2<<<1, 256, 0, stream>>>(bsum);
    k_scan3<<<256, 256, 0, stream>>>(offs, bsum, cursor);
    k_scatter<<<N_EDGES / 256, 256, 0, stream>>>(row, col, ew, dis, nidx, cursor, csr);

    // 3. layer 1: aggregate fp16 features (wave/node), then GEMM (+b1, relu)
    k_agg0<<<N_NODES / 4, 256, 0, stream>>>((const __half2*)cf16, nidx, dis, offs, csr,
                                            (float2*)aggX);
    k_gemm1<<<N_NODES / 32, 256, 0, stream>>>(aggX, W1, b1, h1);

    // 4. layer 2: GEMM -> fp16, aggregate + relu + pool scatter
    k_gemm2<<<N_NODES / 32, 256, 0, stream>>>(h1, W2, xw2h);
    k_agg2_pool<<<N_NODES / 4, 256, 0, stream>>>((const __half2*)xw2h, b2, dis, offs, csr,
                                                 bidx, pool);

    // 5. final divide
    k_final<<<(N_GRAPH * O_DIM + 255) / 256, 256, 0, stream>>>(pool, cntf, out);
}

// Round 6
// 660.163 us; speedup vs baseline: 4.8723x; 1.1980x over previous
//
#include <hip/hip_runtime.h>
#include <hip/hip_fp16.h>
#include <math.h>

// Problem constants (match reference)
constexpr int N_NODES = 65536;
constexpr int N_EDGES = 2097152;
constexpr int F_IN    = 128;
constexpr int H_DIM   = 256;
constexpr int O_DIM   = 128;
constexpr int N_GRAPH = 256;
constexpr int V_SIZE  = 1000;

constexpr float FXP = 16777216.0f;   // 2^24 fixed-point scale for edge weights

// ---------------- init: dc = (cnt=0 | deg=1.0 fixed), pool=0, cf16 ----------

__global__ void k_init(unsigned long long* __restrict__ dc, float* __restrict__ pool,
                       const float* __restrict__ cf, __half* __restrict__ cf16) {
    int i = blockIdx.x * blockDim.x + threadIdx.x;
    dc[i] = 16777216ULL;   // deg = 1.0 (self-loop), cnt = 0
    if (i < N_GRAPH * O_DIM + N_GRAPH) pool[i] = 0.0f;
    // V_SIZE*F_IN = 128000 > 65536 threads: 2 elements per thread
    if (i < V_SIZE * F_IN) cf16[i] = __float2half(cf[i]);
    int i2 = i + N_NODES;
    if (i2 < V_SIZE * F_IN) cf16[i2] = __float2half(cf[i2]);
}

// ---------------- fused degree+count: ONE packed u64 atomic per edge --------

__global__ void k_deg_count(const int* __restrict__ col, const float* __restrict__ ew,
                            unsigned long long* __restrict__ dc) {
    int e = blockIdx.x * blockDim.x + threadIdx.x;
    int c = col[e];
    unsigned long long add = (1ULL << 40) |
        (unsigned long long)(unsigned)(ew[e] * FXP + 0.5f);
    atomicAdd(&dc[c], add);
}

// ---------------- decode: dis = rsqrt(deg), cnt_i = count; batch counts -----

__global__ void k_dis(const unsigned long long* __restrict__ dc, float* __restrict__ dis,
                      int* __restrict__ cnt_i, const int* __restrict__ batch,
                      float* __restrict__ cntf) {
    int i = blockIdx.x * blockDim.x + threadIdx.x;
    unsigned long long v = dc[i];
    float d = (float)(v & 0xFFFFFFFFFFULL) * (1.0f / FXP);
    dis[i] = (d > 0.0f) ? 1.0f / sqrtf(fmaxf(d, 1e-30f)) : 0.0f;
    cnt_i[i] = (int)(v >> 40);
    atomicAdd(&cntf[batch[i]], 1.0f);
}

// ---------------- CSR scan ----------------

__global__ void k_scan1(const int* __restrict__ cnt, int* __restrict__ offs,
                        int* __restrict__ bsum) {
    __shared__ int s[256];
    int tid = threadIdx.x;
    int i = blockIdx.x * 256 + tid;
    int v = cnt[i];
    s[tid] = v;
    __syncthreads();
    for (int d = 1; d < 256; d <<= 1) {
        int t = (tid >= d) ? s[tid - d] : 0;
        __syncthreads();
        s[tid] += t;
        __syncthreads();
    }
    offs[i] = s[tid] - v;
    if (tid == 255) bsum[blockIdx.x] = s[255];
}

__global__ void k_scan2(int* __restrict__ bsum) {
    __shared__ int s[256];
    int tid = threadIdx.x;
    int v = bsum[tid];
    s[tid] = v;
    __syncthreads();
    for (int d = 1; d < 256; d <<= 1) {
        int t = (tid >= d) ? s[tid - d] : 0;
        __syncthreads();
        s[tid] += t;
        __syncthreads();
    }
    bsum[tid] = s[tid] - v;
}

__global__ void k_scan3(int* __restrict__ offs, const int* __restrict__ bsum,
                        int* __restrict__ cursor) {
    int i = blockIdx.x * 256 + threadIdx.x;
    int o = offs[i] + bsum[blockIdx.x];
    offs[i] = o;
    cursor[i] = o;
    if (i == 0) offs[N_NODES] = N_EDGES;
}

// ---------------- scatter: packed (src<<10 | vocab, nrm) int2 ----------------

__global__ void k_scatter(const int* __restrict__ row, const int* __restrict__ col,
                          const float* __restrict__ ew, const float* __restrict__ dis,
                          const int* __restrict__ nidx, int* __restrict__ cursor,
                          int2* __restrict__ csr) {
    int e = blockIdx.x * blockDim.x + threadIdx.x;
    int r = row[e], c = col[e];
    float nrm = dis[r] * ew[e] * dis[c];
    int packed = (r << 10) | nidx[r];
    int slot = atomicAdd(&cursor[c], 1);
    int2 ent; ent.x = packed; ent.y = __float_as_int(nrm);
    csr[slot] = ent;
}

// ---------------- layer-1 aggregation (wave per node, unroll 8) --------------

__global__ void k_agg0(const __half2* __restrict__ cf16, const int* __restrict__ nidx,
                       const float* __restrict__ dis, const int* __restrict__ offs,
                       const int2* __restrict__ csr, float2* __restrict__ aggX) {
    int wave = threadIdx.x >> 6;
    int lane = threadIdx.x & 63;
    int c = blockIdx.x * 4 + wave;
    float d = dis[c];
    float2 self = __half22float2(cf16[(size_t)nidx[c] * 64 + lane]);
    float dd = d * d;
    float2 acc;
    acc.x = self.x * dd;
    acc.y = self.y * dd;
    int s0 = offs[c], s1 = offs[c + 1];
    int s = s0;
    for (; s + 8 <= s1; s += 8) {
        int2 e[8];
        #pragma unroll
        for (int u = 0; u < 8; ++u) e[u] = csr[s + u];
        float2 v[8];
        #pragma unroll
        for (int u = 0; u < 8; ++u)
            v[u] = __half22float2(cf16[(size_t)(e[u].x & 1023) * 64 + lane]);
        #pragma unroll
        for (int u = 0; u < 8; ++u) {
            float n = __int_as_float(e[u].y);
            acc.x += v[u].x * n; acc.y += v[u].y * n;
        }
    }
    for (; s < s1; ++s) {
        int2 e0 = csr[s];
        float2 v0 = __half22float2(cf16[(size_t)(e0.x & 1023) * 64 + lane]);
        float n0 = __int_as_float(e0.y);
        acc.x += v0.x * n0; acc.y += v0.y * n0;
    }
    aggX[(size_t)c * 64 + lane] = acc;
}

// ---------------- GEMM1: aggX [N,128] @ W1 + b1, relu -> h1 [N,256] ----------

__global__ void k_gemm1(const float* __restrict__ aggX, const float* __restrict__ W1,
                        const float* __restrict__ b1, float* __restrict__ h1) {
    __shared__ float xs[32 * F_IN];   // 16 KB
    int nb = blockIdx.x * 32;
    int t  = threadIdx.x;
    const float4* src = (const float4*)(aggX + (size_t)nb * F_IN);
    float4* dst = (float4*)xs;
    #pragma unroll
    for (int p = 0; p < 4; ++p) dst[p * 256 + t] = src[p * 256 + t];
    __syncthreads();
    int o  = t & 63;
    int jg = t >> 6;
    const float* xsj = xs + jg * 8 * F_IN;
    float acc[8][4] = {};
    for (int k = 0; k < F_IN; ++k) {
        float w0 = W1[k * H_DIM + o];
        float w1 = W1[k * H_DIM + o + 64];
        float w2 = W1[k * H_DIM + o + 128];
        float w3 = W1[k * H_DIM + o + 192];
        #pragma unroll
        for (int j = 0; j < 8; ++j) {
            float x = xsj[j * F_IN + k];
            acc[j][0] += x * w0; acc[j][1] += x * w1;
            acc[j][2] += x * w2; acc[j][3] += x * w3;
        }
    }
    float bb0 = b1[o], bb1 = b1[o + 64], bb2 = b1[o + 128], bb3 = b1[o + 192];
    #pragma unroll
    for (int j = 0; j < 8; ++j) {
        size_t base = (size_t)(nb + jg * 8 + j) * H_DIM + o;
        float v0 = acc[j][0] + bb0, v1 = acc[j][1] + bb1;
        float v2 = acc[j][2] + bb2, v3 = acc[j][3] + bb3;
        h1[base]       = v0 > 0.f ? v0 : 0.f;
        h1[base + 64]  = v1 > 0.f ? v1 : 0.f;
        h1[base + 128] = v2 > 0.f ? v2 : 0.f;
        h1[base + 192] = v3 > 0.f ? v3 : 0.f;
    }
}

// ---------------- GEMM2: h1 [N,256] @ W2 -> xw2 (fp16) [N,128] ---------------

__global__ void k_gemm2(const float* __restrict__ h1, const float* __restrict__ W2,
                        __half* __restrict__ xw2h) {
    __shared__ float xs[32 * H_DIM];  // 32 KB
    int nb = blockIdx.x * 32;
    int t  = threadIdx.x;
    const float4* src = (const float4*)(h1 + (size_t)nb * H_DIM);
    float4* dst = (float4*)xs;
    #pragma unroll
    for (int p = 0; p < 8; ++p) dst[p * 256 + t] = src[p * 256 + t];
    __syncthreads();
    int o  = t & 63;
    int jg = t >> 6;
    const float* xsj = xs + jg * 8 * H_DIM;
    float acc[8][2] = {};
    for (int k = 0; k < H_DIM; ++k) {
        float w0 = W2[k * O_DIM + o];
        float w1 = W2[k * O_DIM + o + 64];
        #pragma unroll
        for (int j = 0; j < 8; ++j) {
            float x = xsj[j * H_DIM + k];
            acc[j][0] += x * w0; acc[j][1] += x * w1;
        }
    }
    #pragma unroll
    for (int j = 0; j < 8; ++j) {
        size_t base = (size_t)(nb + jg * 8 + j) * O_DIM + o;
        xw2h[base]      = __float2half(acc[j][0]);
        xw2h[base + 64] = __float2half(acc[j][1]);
    }
}

// ---------------- layer-2 agg + relu + LDS-reduced pool (4 nodes/block) ------

__global__ void k_agg2_pool(const __half2* __restrict__ xw2h, const float* __restrict__ b2,
                            const float* __restrict__ dis, const int* __restrict__ offs,
                            const int2* __restrict__ csr, const int* __restrict__ batch,
                            float* __restrict__ pool) {
    __shared__ float2 red[4][64];
    __shared__ int bgs[4];
    int wave = threadIdx.x >> 6;
    int lane = threadIdx.x & 63;
    int c = blockIdx.x * 4 + wave;
    float d = dis[c];
    float2 self = __half22float2(xw2h[(size_t)c * 64 + lane]);
    float2 bb = ((const float2*)b2)[lane];
    float dd = d * d;
    float2 acc;
    acc.x = bb.x + self.x * dd;
    acc.y = bb.y + self.y * dd;
    int s0 = offs[c], s1 = offs[c + 1];
    int s = s0;
    for (; s + 8 <= s1; s += 8) {
        int2 e[8];
        #pragma unroll
        for (int u = 0; u < 8; ++u) e[u] = csr[s + u];
        float2 v[8];
        #pragma unroll
        for (int u = 0; u < 8; ++u)
            v[u] = __half22float2(xw2h[(size_t)(e[u].x >> 10) * 64 + lane]);
        #pragma unroll
        for (int u = 0; u < 8; ++u) {
            float n = __int_as_float(e[u].y);
            acc.x += v[u].x * n; acc.y += v[u].y * n;
        }
    }
    for (; s < s1; ++s) {
        int2 e0 = csr[s];
        float2 v0 = __half22float2(xw2h[(size_t)(e0.x >> 10) * 64 + lane]);
        float n0 = __int_as_float(e0.y);
        acc.x += v0.x * n0; acc.y += v0.y * n0;
    }
    acc.x = acc.x > 0.0f ? acc.x : 0.0f;
    acc.y = acc.y > 0.0f ? acc.y : 0.0f;
    // batch_index is sorted -> block's 4 nodes usually share a graph.
    red[wave][lane] = acc;
    if (lane == 0) bgs[wave] = batch[c];
    __syncthreads();
    if (wave == 0) {
        float2 a = red[0][lane];
        int cg = bgs[0];
        #pragma unroll
        for (int w = 1; w < 4; ++w) {
            int g = bgs[w];
            float2 r = red[w][lane];
            if (g == cg) { a.x += r.x; a.y += r.y; }
            else {
                atomicAdd(&pool[cg * O_DIM + 2 * lane], a.x);
                atomicAdd(&pool[cg * O_DIM + 2 * lane + 1], a.y);
                a = r; cg = g;
            }
        }
        atomicAdd(&pool[cg * O_DIM + 2 * lane], a.x);
        atomicAdd(&pool[cg * O_DIM + 2 * lane + 1], a.y);
    }
}

__global__ void k_final(const float* __restrict__ pool, const float* __restrict__ cnt,
                        float* __restrict__ out) {
    int t = blockIdx.x * blockDim.x + threadIdx.x;
    if (t < N_GRAPH * O_DIM) {
        int g = t / O_DIM;
        out[t] = pool[t] / fmaxf(cnt[g], 1.0f);
    }
}

// ---------------- launch ----------------

extern "C" void kernel_launch(void* const* d_in, const int* in_sizes, int n_in,
                              void* d_out, int out_size, void* d_ws, size_t ws_size,
                              hipStream_t stream) {
    const float* cf   = (const float*)d_in[0];   // [V,128]
    const float* W1   = (const float*)d_in[1];   // [128,256]
    const float* b1   = (const float*)d_in[2];   // [256]
    const float* W2   = (const float*)d_in[3];   // [256,128]
    const float* b2   = (const float*)d_in[4];   // [128]
    const float* ew   = (const float*)d_in[5];   // [E]
    const int*   nidx = (const int*)d_in[6];     // [N]
    const int*   eidx = (const int*)d_in[7];     // [2,E]
    const int*   bidx = (const int*)d_in[8];     // [N]
    float* out = (float*)d_out;

    const int* row = eidx;            // source
    const int* col = eidx + N_EDGES;  // target

    // workspace layout (bytes)
    char* ws = (char*)d_ws;
    size_t off = 0;
    unsigned long long* dc = (unsigned long long*)(ws + off); off += (size_t)N_NODES * 8;
    float* dis    = (float*)(ws + off); off += (size_t)N_NODES * 4;
    int*   cnt_i  = (int*)  (ws + off); off += (size_t)N_NODES * 4;
    int*   offs   = (int*)  (ws + off); off += (size_t)(N_NODES + 16) * 4;
    int*   cursor = (int*)  (ws + off); off += (size_t)N_NODES * 4;
    int*   bsum   = (int*)  (ws + off); off += 4096;
    int2*  csr    = (int2*) (ws + off); off += (size_t)N_EDGES * 8;       // 16M
    float* pool   = (float*)(ws + off); off += (size_t)(N_GRAPH * O_DIM + N_GRAPH) * 4;
    __half* cf16  = (__half*)(ws + off); off += (size_t)V_SIZE * F_IN * 2; // 256K
    off = (off + 255) & ~(size_t)255;
    float* aggX   = (float*)(ws + off); off += (size_t)N_NODES * F_IN * 4; // 32M
    float* h1     = (float*)(ws + off);                                    // 64M
    __half* xw2h  = (__half*)aggX;   // aggX dead after gemm1
    float* cntf   = pool + N_GRAPH * O_DIM;

    // 1. init + packed degree/count + decode
    k_init<<<N_NODES / 256, 256, 0, stream>>>(dc, pool, cf, cf16);
    k_deg_count<<<N_EDGES / 256, 256, 0, stream>>>(col, ew, dc);
    k_dis<<<N_NODES / 256, 256, 0, stream>>>(dc, dis, cnt_i, bidx, cntf);

    // 2. CSR build
    k_scan1<<<256, 256, 0, stream>>>(cnt_i, offs, bsum);
    k_scan2<<<1, 256, 0, stream>>>(bsum);
    k_scan3<<<256, 256, 0, stream>>>(offs, bsum, cursor);
    k_scatter<<<N_EDGES / 256, 256, 0, stream>>>(row, col, ew, dis, nidx, cursor, csr);

    // 3. layer 1: aggregate fp16 features (wave/node), then GEMM (+b1, relu)
    k_agg0<<<N_NODES / 4, 256, 0, stream>>>((const __half2*)cf16, nidx, dis, offs, csr,
                                            (float2*)aggX);
    k_gemm1<<<N_NODES / 32, 256, 0, stream>>>(aggX, W1, b1, h1);

    // 4. layer 2: GEMM -> fp16, aggregate + relu + LDS-reduced pool
    k_gemm2<<<N_NODES / 32, 256, 0, stream>>>(h1, W2, xw2h);
    k_agg2_pool<<<N_NODES / 4, 256, 0, stream>>>((const __half2*)xw2h, b2, dis, offs, csr,
                                                 bidx, pool);

    // 5. final divide
    k_final<<<(N_GRAPH * O_DIM + 255) / 256, 256, 0, stream>>>(pool, cntf, out);
}

// Round 7
// 561.213 us; speedup vs baseline: 5.7313x; 1.1763x over previous
//
#include <hip/hip_runtime.h>
#include <hip/hip_fp16.h>
#include <math.h>

// Problem constants (match reference)
constexpr int N_NODES = 65536;
constexpr int N_EDGES = 2097152;
constexpr int F_IN    = 128;
constexpr int H_DIM   = 256;
constexpr int O_DIM   = 128;
constexpr int N_GRAPH = 256;
constexpr int V_SIZE  = 1000;

// 256 buckets of 256 nodes (bucket = col>>8); 256 edge-blocks of 8192 edges.
constexpr int EPB = 8192;   // edges per hist/part block
constexpr int NBLK = N_EDGES / EPB;   // 256

// ---------------- init: pool=0 (incl cnt), cf16 convert ----------------

__global__ void k_init(float* __restrict__ pool, const float* __restrict__ cf,
                       __half* __restrict__ cf16) {
    int i = blockIdx.x * blockDim.x + threadIdx.x;
    if (i < N_GRAPH * O_DIM + N_GRAPH) pool[i] = 0.0f;
    if (i < V_SIZE * F_IN) cf16[i] = __float2half(cf[i]);
    int i2 = i + N_NODES;
    if (i2 < V_SIZE * F_IN) cf16[i2] = __float2half(cf[i2]);
}

// ---------------- stage A: per-block bucket histogram (LDS) ----------------

__global__ void k_hist(const int* __restrict__ col, int* __restrict__ hist) {
    __shared__ int h[256];
    int t = threadIdx.x;
    h[t] = 0;
    __syncthreads();
    int base = blockIdx.x * EPB;
    #pragma unroll
    for (int i = 0; i < EPB / 256; ++i)
        atomicAdd(&h[col[base + i * 256 + t] >> 8], 1);
    __syncthreads();
    hist[t * NBLK + blockIdx.x] = h[t];   // bucket-major layout for the scan
}

// ---------------- 65536-entry exclusive scan (3 kernels) ----------------

__global__ void k_scan1(const int* __restrict__ in, int* __restrict__ out,
                        int* __restrict__ bsum) {
    __shared__ int s[256];
    int tid = threadIdx.x;
    int i = blockIdx.x * 256 + tid;
    int v = in[i];
    s[tid] = v;
    __syncthreads();
    for (int d = 1; d < 256; d <<= 1) {
        int t = (tid >= d) ? s[tid - d] : 0;
        __syncthreads();
        s[tid] += t;
        __syncthreads();
    }
    out[i] = s[tid] - v;
    if (tid == 255) bsum[blockIdx.x] = s[255];
}

__global__ void k_scan2(int* __restrict__ bsum) {
    __shared__ int s[256];
    int tid = threadIdx.x;
    int v = bsum[tid];
    s[tid] = v;
    __syncthreads();
    for (int d = 1; d < 256; d <<= 1) {
        int t = (tid >= d) ? s[tid - d] : 0;
        __syncthreads();
        s[tid] += t;
        __syncthreads();
    }
    bsum[tid] = s[tid] - v;
}

__global__ void k_scan3(int* __restrict__ out, const int* __restrict__ bsum) {
    int i = blockIdx.x * 256 + threadIdx.x;
    out[i] += bsum[blockIdx.x];
}

// ---------------- stage C: partition edges into buckets (LDS cursors) -------
// record: {src<<10|vocab, ew bits, dst&255, pad}

__global__ void k_part(const int* __restrict__ row, const int* __restrict__ col,
                       const float* __restrict__ ew, const int* __restrict__ nidx,
                       const int* __restrict__ hoffs, int4* __restrict__ part) {
    __shared__ int cur[256];
    int t = threadIdx.x;
    cur[t] = hoffs[t * NBLK + blockIdx.x];
    __syncthreads();
    int base = blockIdx.x * EPB;
    for (int i = 0; i < EPB / 256; ++i) {
        int e = base + i * 256 + t;
        int r = row[e], c = col[e];
        float w = ew[e];
        int slot = atomicAdd(&cur[c >> 8], 1);
        int4 rec;
        rec.x = (r << 10) | nidx[r];
        rec.y = __float_as_int(w);
        rec.z = c & 255;
        rec.w = 0;
        part[slot] = rec;
    }
}

// ---------------- stage D: per-bucket build: deg/dis, offs, final CSR -------

__global__ void k_build(const int* __restrict__ hoffs, const int4* __restrict__ part,
                        int2* __restrict__ csr, float* __restrict__ dis,
                        int* __restrict__ offs) {
    __shared__ int   cnt[256];
    __shared__ float dsum[256];
    __shared__ int   sc[256];
    __shared__ int   cur[256];
    int t = threadIdx.x;
    int bucket = blockIdx.x;
    cnt[t] = 0;
    dsum[t] = 0.0f;
    __syncthreads();
    int start = hoffs[bucket * NBLK];
    int end   = (bucket == 255) ? N_EDGES : hoffs[(bucket + 1) * NBLK];
    for (int j = start + t; j < end; j += 256) {
        int4 rec = part[j];
        atomicAdd(&cnt[rec.z], 1);
        atomicAdd(&dsum[rec.z], __int_as_float(rec.y));
    }
    __syncthreads();
    // degree (exact fp32) -> dis
    float deg = 1.0f + dsum[t];                 // self-loop weight 1
    dis[bucket * 256 + t] = 1.0f / sqrtf(fmaxf(deg, 1e-30f));
    // exclusive scan of per-node counts
    int v = cnt[t];
    sc[t] = v;
    __syncthreads();
    for (int d = 1; d < 256; d <<= 1) {
        int x = (t >= d) ? sc[t - d] : 0;
        __syncthreads();
        sc[t] += x;
        __syncthreads();
    }
    int node_off = start + sc[t] - v;
    offs[bucket * 256 + t] = node_off;
    cur[t] = node_off;
    if (bucket == 255 && t == 255) offs[N_NODES] = N_EDGES;
    __syncthreads();
    // scatter bucket records into final CSR (per-node contiguous)
    for (int j = start + t; j < end; j += 256) {
        int4 rec = part[j];
        int slot = atomicAdd(&cur[rec.z], 1);
        int2 e;
        e.x = rec.x;
        e.y = rec.y;          // still raw ew; k_nrm scales by dis[src]
        csr[slot] = e;
    }
}

// ---------------- nrm transform: csr.y = dis[src] * ew ----------------
// (dis[dst] factors out of the aggregation and is applied in the agg kernels)

__global__ void k_nrm(int2* __restrict__ csr, const float* __restrict__ dis) {
    int i = blockIdx.x * blockDim.x + threadIdx.x;
    int2 e = csr[i];
    e.y = __float_as_int(dis[e.x >> 10] * __int_as_float(e.y));
    csr[i] = e;
}

// ---------------- batch counts ----------------

__global__ void k_cnt(const int* __restrict__ batch, float* __restrict__ cntf) {
    int i = blockIdx.x * blockDim.x + threadIdx.x;
    atomicAdd(&cntf[batch[i]], 1.0f);
}

// ---------------- layer-1 aggregation (wave per node, unroll 8) --------------

__global__ void k_agg0(const __half2* __restrict__ cf16, const int* __restrict__ nidx,
                       const float* __restrict__ dis, const int* __restrict__ offs,
                       const int2* __restrict__ csr, float2* __restrict__ aggX) {
    int wave = threadIdx.x >> 6;
    int lane = threadIdx.x & 63;
    int c = blockIdx.x * 4 + wave;
    float d = dis[c];
    float2 self = __half22float2(cf16[(size_t)nidx[c] * 64 + lane]);
    float2 esum = {0.f, 0.f};
    int s0 = offs[c], s1 = offs[c + 1];
    int s = s0;
    for (; s + 8 <= s1; s += 8) {
        int2 e[8];
        #pragma unroll
        for (int u = 0; u < 8; ++u) e[u] = csr[s + u];
        float2 v[8];
        #pragma unroll
        for (int u = 0; u < 8; ++u)
            v[u] = __half22float2(cf16[(size_t)(e[u].x & 1023) * 64 + lane]);
        #pragma unroll
        for (int u = 0; u < 8; ++u) {
            float n = __int_as_float(e[u].y);
            esum.x += v[u].x * n; esum.y += v[u].y * n;
        }
    }
    for (; s < s1; ++s) {
        int2 e0 = csr[s];
        float2 v0 = __half22float2(cf16[(size_t)(e0.x & 1023) * 64 + lane]);
        float n0 = __int_as_float(e0.y);
        esum.x += v0.x * n0; esum.y += v0.y * n0;
    }
    float dd = d * d;
    float2 acc;
    acc.x = self.x * dd + d * esum.x;
    acc.y = self.y * dd + d * esum.y;
    aggX[(size_t)c * 64 + lane] = acc;
}

// ---------------- GEMM1: aggX [N,128] @ W1 + b1, relu -> h1 [N,256] ----------

__global__ void k_gemm1(const float* __restrict__ aggX, const float* __restrict__ W1,
                        const float* __restrict__ b1, float* __restrict__ h1) {
    __shared__ float xs[32 * F_IN];   // 16 KB
    int nb = blockIdx.x * 32;
    int t  = threadIdx.x;
    const float4* src = (const float4*)(aggX + (size_t)nb * F_IN);
    float4* dst = (float4*)xs;
    #pragma unroll
    for (int p = 0; p < 4; ++p) dst[p * 256 + t] = src[p * 256 + t];
    __syncthreads();
    int o  = t & 63;
    int jg = t >> 6;
    const float* xsj = xs + jg * 8 * F_IN;
    float acc[8][4] = {};
    for (int k = 0; k < F_IN; ++k) {
        float w0 = W1[k * H_DIM + o];
        float w1 = W1[k * H_DIM + o + 64];
        float w2 = W1[k * H_DIM + o + 128];
        float w3 = W1[k * H_DIM + o + 192];
        #pragma unroll
        for (int j = 0; j < 8; ++j) {
            float x = xsj[j * F_IN + k];
            acc[j][0] += x * w0; acc[j][1] += x * w1;
            acc[j][2] += x * w2; acc[j][3] += x * w3;
        }
    }
    float bb0 = b1[o], bb1 = b1[o + 64], bb2 = b1[o + 128], bb3 = b1[o + 192];
    #pragma unroll
    for (int j = 0; j < 8; ++j) {
        size_t base = (size_t)(nb + jg * 8 + j) * H_DIM + o;
        float v0 = acc[j][0] + bb0, v1 = acc[j][1] + bb1;
        float v2 = acc[j][2] + bb2, v3 = acc[j][3] + bb3;
        h1[base]       = v0 > 0.f ? v0 : 0.f;
        h1[base + 64]  = v1 > 0.f ? v1 : 0.f;
        h1[base + 128] = v2 > 0.f ? v2 : 0.f;
        h1[base + 192] = v3 > 0.f ? v3 : 0.f;
    }
}

// ---------------- GEMM2: h1 [N,256] @ W2 -> xw2 (fp16) [N,128] ---------------

__global__ void k_gemm2(const float* __restrict__ h1, const float* __restrict__ W2,
                        __half* __restrict__ xw2h) {
    __shared__ float xs[32 * H_DIM];  // 32 KB
    int nb = blockIdx.x * 32;
    int t  = threadIdx.x;
    const float4* src = (const float4*)(h1 + (size_t)nb * H_DIM);
    float4* dst = (float4*)xs;
    #pragma unroll
    for (int p = 0; p < 8; ++p) dst[p * 256 + t] = src[p * 256 + t];
    __syncthreads();
    int o  = t & 63;
    int jg = t >> 6;
    const float* xsj = xs + jg * 8 * H_DIM;
    float acc[8][2] = {};
    for (int k = 0; k < H_DIM; ++k) {
        float w0 = W2[k * O_DIM + o];
        float w1 = W2[k * O_DIM + o + 64];
        #pragma unroll
        for (int j = 0; j < 8; ++j) {
            float x = xsj[j * H_DIM + k];
            acc[j][0] += x * w0; acc[j][1] += x * w1;
        }
    }
    #pragma unroll
    for (int j = 0; j < 8; ++j) {
        size_t base = (size_t)(nb + jg * 8 + j) * O_DIM + o;
        xw2h[base]      = __float2half(acc[j][0]);
        xw2h[base + 64] = __float2half(acc[j][1]);
    }
}

// ---------------- layer-2 agg + relu + LDS-reduced pool (4 nodes/block) ------

__global__ void k_agg2_pool(const __half2* __restrict__ xw2h, const float* __restrict__ b2,
                            const float* __restrict__ dis, const int* __restrict__ offs,
                            const int2* __restrict__ csr, const int* __restrict__ batch,
                            float* __restrict__ pool) {
    __shared__ float2 red[4][64];
    __shared__ int bgs[4];
    int wave = threadIdx.x >> 6;
    int lane = threadIdx.x & 63;
    int c = blockIdx.x * 4 + wave;
    float d = dis[c];
    float2 self = __half22float2(xw2h[(size_t)c * 64 + lane]);
    float2 bb = ((const float2*)b2)[lane];
    float2 esum = {0.f, 0.f};
    int s0 = offs[c], s1 = offs[c + 1];
    int s = s0;
    for (; s + 8 <= s1; s += 8) {
        int2 e[8];
        #pragma unroll
        for (int u = 0; u < 8; ++u) e[u] = csr[s + u];
        float2 v[8];
        #pragma unroll
        for (int u = 0; u < 8; ++u)
            v[u] = __half22float2(xw2h[(size_t)(e[u].x >> 10) * 64 + lane]);
        #pragma unroll
        for (int u = 0; u < 8; ++u) {
            float n = __int_as_float(e[u].y);
            esum.x += v[u].x * n; esum.y += v[u].y * n;
        }
    }
    for (; s < s1; ++s) {
        int2 e0 = csr[s];
        float2 v0 = __half22float2(xw2h[(size_t)(e0.x >> 10) * 64 + lane]);
        float n0 = __int_as_float(e0.y);
        esum.x += v0.x * n0; esum.y += v0.y * n0;
    }
    float dd = d * d;
    float2 acc;
    acc.x = bb.x + self.x * dd + d * esum.x;
    acc.y = bb.y + self.y * dd + d * esum.y;
    acc.x = acc.x > 0.0f ? acc.x : 0.0f;
    acc.y = acc.y > 0.0f ? acc.y : 0.0f;
    // batch_index sorted -> block's 4 nodes usually share a graph
    red[wave][lane] = acc;
    if (lane == 0) bgs[wave] = batch[c];
    __syncthreads();
    if (wave == 0) {
        float2 a = red[0][lane];
        int cg = bgs[0];
        #pragma unroll
        for (int w = 1; w < 4; ++w) {
            int g = bgs[w];
            float2 r = red[w][lane];
            if (g == cg) { a.x += r.x; a.y += r.y; }
            else {
                atomicAdd(&pool[cg * O_DIM + 2 * lane], a.x);
                atomicAdd(&pool[cg * O_DIM + 2 * lane + 1], a.y);
                a = r; cg = g;
            }
        }
        atomicAdd(&pool[cg * O_DIM + 2 * lane], a.x);
        atomicAdd(&pool[cg * O_DIM + 2 * lane + 1], a.y);
    }
}

__global__ void k_final(const float* __restrict__ pool, const float* __restrict__ cnt,
                        float* __restrict__ out) {
    int t = blockIdx.x * blockDim.x + threadIdx.x;
    if (t < N_GRAPH * O_DIM) {
        int g = t / O_DIM;
        out[t] = pool[t] / fmaxf(cnt[g], 1.0f);
    }
}

// ---------------- launch ----------------

extern "C" void kernel_launch(void* const* d_in, const int* in_sizes, int n_in,
                              void* d_out, int out_size, void* d_ws, size_t ws_size,
                              hipStream_t stream) {
    const float* cf   = (const float*)d_in[0];   // [V,128]
    const float* W1   = (const float*)d_in[1];   // [128,256]
    const float* b1   = (const float*)d_in[2];   // [256]
    const float* W2   = (const float*)d_in[3];   // [256,128]
    const float* b2   = (const float*)d_in[4];   // [128]
    const float* ew   = (const float*)d_in[5];   // [E]
    const int*   nidx = (const int*)d_in[6];     // [N]
    const int*   eidx = (const int*)d_in[7];     // [2,E]
    const int*   bidx = (const int*)d_in[8];     // [N]
    float* out = (float*)d_out;

    const int* row = eidx;            // source
    const int* col = eidx + N_EDGES;  // target

    // workspace layout (bytes)
    char* ws = (char*)d_ws;
    size_t off = 0;
    int*   hist  = (int*)  (ws + off); off += (size_t)N_NODES * 4;          // 256K
    int*   hoffs = (int*)  (ws + off); off += (size_t)N_NODES * 4;          // 256K
    int*   bsum  = (int*)  (ws + off); off += 4096;
    float* dis   = (float*)(ws + off); off += (size_t)N_NODES * 4;          // 256K
    int*   offs  = (int*)  (ws + off); off += (size_t)(N_NODES + 16) * 4;   // 256K
    int2*  csr   = (int2*) (ws + off); off += (size_t)N_EDGES * 8;          // 16M
    float* pool  = (float*)(ws + off); off += (size_t)(N_GRAPH * O_DIM + N_GRAPH) * 4;
    __half* cf16 = (__half*)(ws + off); off += (size_t)V_SIZE * F_IN * 2;   // 256K
    off = (off + 255) & ~(size_t)255;
    float* aggX  = (float*)(ws + off); off += (size_t)N_NODES * F_IN * 4;   // 32M
    float* h1    = (float*)(ws + off);                                      // 64M
    int4*  part  = (int4*)aggX;      // 32M bucket buffer, dead before k_agg0
    __half* xw2h = (__half*)aggX;    // aggX dead after gemm1
    float* cntf  = pool + N_GRAPH * O_DIM;

    // 1. init + bucket histogram + scan
    k_init<<<N_NODES / 256, 256, 0, stream>>>(pool, cf, cf16);
    k_hist<<<NBLK, 256, 0, stream>>>(col, hist);
    k_scan1<<<256, 256, 0, stream>>>(hist, hoffs, bsum);
    k_scan2<<<1, 256, 0, stream>>>(bsum);
    k_scan3<<<256, 256, 0, stream>>>(hoffs, bsum);

    // 2. partition -> per-bucket build (deg/dis/offs/CSR) -> nrm transform
    k_part<<<NBLK, 256, 0, stream>>>(row, col, ew, nidx, hoffs, part);
    k_build<<<256, 256, 0, stream>>>(hoffs, part, csr, dis, offs);
    k_nrm<<<N_EDGES / 256, 256, 0, stream>>>(csr, dis);
    k_cnt<<<N_NODES / 256, 256, 0, stream>>>(bidx, cntf);

    // 3. layer 1: aggregate fp16 features (wave/node), then GEMM (+b1, relu)
    k_agg0<<<N_NODES / 4, 256, 0, stream>>>((const __half2*)cf16, nidx, dis, offs, csr,
                                            (float2*)aggX);
    k_gemm1<<<N_NODES / 32, 256, 0, stream>>>(aggX, W1, b1, h1);

    // 4. layer 2: GEMM -> fp16, aggregate + relu + LDS-reduced pool
    k_gemm2<<<N_NODES / 32, 256, 0, stream>>>(h1, W2, xw2h);
    k_agg2_pool<<<N_NODES / 4, 256, 0, stream>>>((const __half2*)xw2h, b2, dis, offs, csr,
                                                 bidx, pool);

    // 5. final divide
    k_final<<<(N_GRAPH * O_DIM + 255) / 256, 256, 0, stream>>>(pool, cntf, out);
}

// Round 8
// 471.466 us; speedup vs baseline: 6.8223x; 1.1904x over previous
//
#include <hip/hip_runtime.h>
#include <hip/hip_fp16.h>
#include <math.h>

// Problem constants (match reference)
constexpr int N_NODES = 65536;
constexpr int N_EDGES = 2097152;
constexpr int F_IN    = 128;
constexpr int H_DIM   = 256;
constexpr int O_DIM   = 128;
constexpr int N_GRAPH = 256;
constexpr int V_SIZE  = 1000;

// 256 buckets of 256 nodes (bucket = col>>8); 256 edge-blocks of 8192 edges.
constexpr int EPB = 8192;   // edges per hist/part block
constexpr int NBLK = N_EDGES / EPB;   // 256

// ---------------- init: pool=0, cf16 convert ----------------

__global__ void k_init(float* __restrict__ pool, const float* __restrict__ cf,
                       __half* __restrict__ cf16) {
    int i = blockIdx.x * blockDim.x + threadIdx.x;
    if (i < N_GRAPH * O_DIM) pool[i] = 0.0f;
    if (i < V_SIZE * F_IN) cf16[i] = __float2half(cf[i]);
    int i2 = i + N_NODES;
    if (i2 < V_SIZE * F_IN) cf16[i2] = __float2half(cf[i2]);
}

// ---------------- graph counts via binary search (batch_index is sorted) -----

__global__ void k_gcount(const int* __restrict__ batch, float* __restrict__ cntf) {
    int g = threadIdx.x;   // 256 graphs, 1 block
    int lo = 0, hi = N_NODES;
    while (lo < hi) { int m = (lo + hi) >> 1; if (batch[m] < g) lo = m + 1; else hi = m; }
    int start = lo;
    lo = 0; hi = N_NODES;
    while (lo < hi) { int m = (lo + hi) >> 1; if (batch[m] <= g) lo = m + 1; else hi = m; }
    cntf[g] = (float)(lo - start);
}

// ---------------- stage A: per-block bucket histogram (LDS) ----------------

__global__ void k_hist(const int* __restrict__ col, int* __restrict__ hist) {
    __shared__ int h[256];
    int t = threadIdx.x;
    h[t] = 0;
    __syncthreads();
    int base = blockIdx.x * EPB;
    #pragma unroll
    for (int i = 0; i < EPB / 256; ++i)
        atomicAdd(&h[col[base + i * 256 + t] >> 8], 1);
    __syncthreads();
    hist[t * NBLK + blockIdx.x] = h[t];   // bucket-major layout for the scan
}

// ---------------- 65536-entry exclusive scan (3 kernels) ----------------

__global__ void k_scan1(const int* __restrict__ in, int* __restrict__ out,
                        int* __restrict__ bsum) {
    __shared__ int s[256];
    int tid = threadIdx.x;
    int i = blockIdx.x * 256 + tid;
    int v = in[i];
    s[tid] = v;
    __syncthreads();
    for (int d = 1; d < 256; d <<= 1) {
        int t = (tid >= d) ? s[tid - d] : 0;
        __syncthreads();
        s[tid] += t;
        __syncthreads();
    }
    out[i] = s[tid] - v;
    if (tid == 255) bsum[blockIdx.x] = s[255];
}

__global__ void k_scan2(int* __restrict__ bsum) {
    __shared__ int s[256];
    int tid = threadIdx.x;
    int v = bsum[tid];
    s[tid] = v;
    __syncthreads();
    for (int d = 1; d < 256; d <<= 1) {
        int t = (tid >= d) ? s[tid - d] : 0;
        __syncthreads();
        s[tid] += t;
        __syncthreads();
    }
    bsum[tid] = s[tid] - v;
}

__global__ void k_scan3(int* __restrict__ out, const int* __restrict__ bsum) {
    int i = blockIdx.x * 256 + threadIdx.x;
    out[i] += bsum[blockIdx.x];
}

// ---------------- stage C: partition edges into buckets (LDS cursors) -------
// record: {src<<10|vocab, ew bits, dst&255, pad}

__global__ void k_part(const int* __restrict__ row, const int* __restrict__ col,
                       const float* __restrict__ ew, const int* __restrict__ nidx,
                       const int* __restrict__ hoffs, int4* __restrict__ part) {
    __shared__ int cur[256];
    int t = threadIdx.x;
    cur[t] = hoffs[t * NBLK + blockIdx.x];
    __syncthreads();
    int base = blockIdx.x * EPB;
    for (int i = 0; i < EPB / 256; ++i) {
        int e = base + i * 256 + t;
        int r = row[e], c = col[e];
        float w = ew[e];
        int slot = atomicAdd(&cur[c >> 8], 1);
        int4 rec;
        rec.x = (r << 10) | nidx[r];
        rec.y = __float_as_int(w);
        rec.z = c & 255;
        rec.w = 0;
        part[slot] = rec;
    }
}

// ---------------- stage D: per-bucket build: deg/dis, offs, final CSR -------

__global__ void k_build(const int* __restrict__ hoffs, const int4* __restrict__ part,
                        int2* __restrict__ csr, float* __restrict__ dis,
                        int* __restrict__ offs) {
    __shared__ int   cnt[256];
    __shared__ float dsum[256];
    __shared__ int   sc[256];
    __shared__ int   cur[256];
    int t = threadIdx.x;
    int bucket = blockIdx.x;
    cnt[t] = 0;
    dsum[t] = 0.0f;
    __syncthreads();
    int start = hoffs[bucket * NBLK];
    int end   = (bucket == 255) ? N_EDGES : hoffs[(bucket + 1) * NBLK];
    for (int j = start + t; j < end; j += 256) {
        int4 rec = part[j];
        atomicAdd(&cnt[rec.z], 1);
        atomicAdd(&dsum[rec.z], __int_as_float(rec.y));
    }
    __syncthreads();
    // degree (exact fp32) -> dis
    float deg = 1.0f + dsum[t];                 // self-loop weight 1
    dis[bucket * 256 + t] = 1.0f / sqrtf(fmaxf(deg, 1e-30f));
    // exclusive scan of per-node counts
    int v = cnt[t];
    sc[t] = v;
    __syncthreads();
    for (int d = 1; d < 256; d <<= 1) {
        int x = (t >= d) ? sc[t - d] : 0;
        __syncthreads();
        sc[t] += x;
        __syncthreads();
    }
    int node_off = start + sc[t] - v;
    offs[bucket * 256 + t] = node_off;
    cur[t] = node_off;
    if (bucket == 255 && t == 255) offs[N_NODES] = N_EDGES;
    __syncthreads();
    // scatter bucket records into final CSR (per-node contiguous)
    for (int j = start + t; j < end; j += 256) {
        int4 rec = part[j];
        int slot = atomicAdd(&cur[rec.z], 1);
        int2 e;
        e.x = rec.x;
        e.y = rec.y;          // still raw ew; k_nrm scales by dis[src]
        csr[slot] = e;
    }
}

// ---------------- nrm transform: csr.y = dis[src] * ew ----------------
// (dis[dst] factors out of the aggregation and is applied in the agg kernels)

__global__ void k_nrm(int2* __restrict__ csr, const float* __restrict__ dis) {
    int i = blockIdx.x * blockDim.x + threadIdx.x;
    int2 e = csr[i];
    e.y = __float_as_int(dis[e.x >> 10] * __int_as_float(e.y));
    csr[i] = e;
}

// ---------------- layer-1 aggregation (wave per node, unroll 8) --------------

__global__ void k_agg0(const __half2* __restrict__ cf16, const int* __restrict__ nidx,
                       const float* __restrict__ dis, const int* __restrict__ offs,
                       const int2* __restrict__ csr, float2* __restrict__ aggX) {
    int wave = threadIdx.x >> 6;
    int lane = threadIdx.x & 63;
    int c = blockIdx.x * 4 + wave;
    float d = dis[c];
    float2 self = __half22float2(cf16[(size_t)nidx[c] * 64 + lane]);
    float2 esum = {0.f, 0.f};
    int s0 = offs[c], s1 = offs[c + 1];
    int s = s0;
    for (; s + 8 <= s1; s += 8) {
        int2 e[8];
        #pragma unroll
        for (int u = 0; u < 8; ++u) e[u] = csr[s + u];
        float2 v[8];
        #pragma unroll
        for (int u = 0; u < 8; ++u)
            v[u] = __half22float2(cf16[(size_t)(e[u].x & 1023) * 64 + lane]);
        #pragma unroll
        for (int u = 0; u < 8; ++u) {
            float n = __int_as_float(e[u].y);
            esum.x += v[u].x * n; esum.y += v[u].y * n;
        }
    }
    for (; s < s1; ++s) {
        int2 e0 = csr[s];
        float2 v0 = __half22float2(cf16[(size_t)(e0.x & 1023) * 64 + lane]);
        float n0 = __int_as_float(e0.y);
        esum.x += v0.x * n0; esum.y += v0.y * n0;
    }
    float dd = d * d;
    float2 acc;
    acc.x = self.x * dd + d * esum.x;
    acc.y = self.y * dd + d * esum.y;
    aggX[(size_t)c * 64 + lane] = acc;
}

// ---------------- GEMM1: aggX [N,128] @ W1 + b1, relu -> h1 [N,256] ----------

__global__ void k_gemm1(const float* __restrict__ aggX, const float* __restrict__ W1,
                        const float* __restrict__ b1, float* __restrict__ h1) {
    __shared__ float xs[32 * F_IN];   // 16 KB
    int nb = blockIdx.x * 32;
    int t  = threadIdx.x;
    const float4* src = (const float4*)(aggX + (size_t)nb * F_IN);
    float4* dst = (float4*)xs;
    #pragma unroll
    for (int p = 0; p < 4; ++p) dst[p * 256 + t] = src[p * 256 + t];
    __syncthreads();
    int o  = t & 63;
    int jg = t >> 6;
    const float* xsj = xs + jg * 8 * F_IN;
    float acc[8][4] = {};
    for (int k = 0; k < F_IN; ++k) {
        float w0 = W1[k * H_DIM + o];
        float w1 = W1[k * H_DIM + o + 64];
        float w2 = W1[k * H_DIM + o + 128];
        float w3 = W1[k * H_DIM + o + 192];
        #pragma unroll
        for (int j = 0; j < 8; ++j) {
            float x = xsj[j * F_IN + k];
            acc[j][0] += x * w0; acc[j][1] += x * w1;
            acc[j][2] += x * w2; acc[j][3] += x * w3;
        }
    }
    float bb0 = b1[o], bb1 = b1[o + 64], bb2 = b1[o + 128], bb3 = b1[o + 192];
    #pragma unroll
    for (int j = 0; j < 8; ++j) {
        size_t base = (size_t)(nb + jg * 8 + j) * H_DIM + o;
        float v0 = acc[j][0] + bb0, v1 = acc[j][1] + bb1;
        float v2 = acc[j][2] + bb2, v3 = acc[j][3] + bb3;
        h1[base]       = v0 > 0.f ? v0 : 0.f;
        h1[base + 64]  = v1 > 0.f ? v1 : 0.f;
        h1[base + 128] = v2 > 0.f ? v2 : 0.f;
        h1[base + 192] = v3 > 0.f ? v3 : 0.f;
    }
}

// ---------------- GEMM2: h1 [N,256] @ W2 -> xw2 (fp16) [N,128] ---------------

__global__ void k_gemm2(const float* __restrict__ h1, const float* __restrict__ W2,
                        __half* __restrict__ xw2h) {
    __shared__ float xs[32 * H_DIM];  // 32 KB
    int nb = blockIdx.x * 32;
    int t  = threadIdx.x;
    const float4* src = (const float4*)(h1 + (size_t)nb * H_DIM);
    float4* dst = (float4*)xs;
    #pragma unroll
    for (int p = 0; p < 8; ++p) dst[p * 256 + t] = src[p * 256 + t];
    __syncthreads();
    int o  = t & 63;
    int jg = t >> 6;
    const float* xsj = xs + jg * 8 * H_DIM;
    float acc[8][2] = {};
    for (int k = 0; k < H_DIM; ++k) {
        float w0 = W2[k * O_DIM + o];
        float w1 = W2[k * O_DIM + o + 64];
        #pragma unroll
        for (int j = 0; j < 8; ++j) {
            float x = xsj[j * H_DIM + k];
            acc[j][0] += x * w0; acc[j][1] += x * w1;
        }
    }
    #pragma unroll
    for (int j = 0; j < 8; ++j) {
        size_t base = (size_t)(nb + jg * 8 + j) * O_DIM + o;
        xw2h[base]      = __float2half(acc[j][0]);
        xw2h[base + 64] = __float2half(acc[j][1]);
    }
}

// ---------------- layer-2 agg + relu + LDS-reduced pool (4 nodes/block) ------

__global__ void k_agg2_pool(const __half2* __restrict__ xw2h, const float* __restrict__ b2,
                            const float* __restrict__ dis, const int* __restrict__ offs,
                            const int2* __restrict__ csr, const int* __restrict__ batch,
                            float* __restrict__ pool) {
    __shared__ float2 red[4][64];
    __shared__ int bgs[4];
    int wave = threadIdx.x >> 6;
    int lane = threadIdx.x & 63;
    int c = blockIdx.x * 4 + wave;
    float d = dis[c];
    float2 self = __half22float2(xw2h[(size_t)c * 64 + lane]);
    float2 bb = ((const float2*)b2)[lane];
    float2 esum = {0.f, 0.f};
    int s0 = offs[c], s1 = offs[c + 1];
    int s = s0;
    for (; s + 8 <= s1; s += 8) {
        int2 e[8];
        #pragma unroll
        for (int u = 0; u < 8; ++u) e[u] = csr[s + u];
        float2 v[8];
        #pragma unroll
        for (int u = 0; u < 8; ++u)
            v[u] = __half22float2(xw2h[(size_t)(e[u].x >> 10) * 64 + lane]);
        #pragma unroll
        for (int u = 0; u < 8; ++u) {
            float n = __int_as_float(e[u].y);
            esum.x += v[u].x * n; esum.y += v[u].y * n;
        }
    }
    for (; s < s1; ++s) {
        int2 e0 = csr[s];
        float2 v0 = __half22float2(xw2h[(size_t)(e0.x >> 10) * 64 + lane]);
        float n0 = __int_as_float(e0.y);
        esum.x += v0.x * n0; esum.y += v0.y * n0;
    }
    float dd = d * d;
    float2 acc;
    acc.x = bb.x + self.x * dd + d * esum.x;
    acc.y = bb.y + self.y * dd + d * esum.y;
    acc.x = acc.x > 0.0f ? acc.x : 0.0f;
    acc.y = acc.y > 0.0f ? acc.y : 0.0f;
    // batch_index sorted -> block's 4 nodes usually share a graph
    red[wave][lane] = acc;
    if (lane == 0) bgs[wave] = batch[c];
    __syncthreads();
    if (wave == 0) {
        float2 a = red[0][lane];
        int cg = bgs[0];
        #pragma unroll
        for (int w = 1; w < 4; ++w) {
            int g = bgs[w];
            float2 r = red[w][lane];
            if (g == cg) { a.x += r.x; a.y += r.y; }
            else {
                atomicAdd(&pool[cg * O_DIM + 2 * lane], a.x);
                atomicAdd(&pool[cg * O_DIM + 2 * lane + 1], a.y);
                a = r; cg = g;
            }
        }
        atomicAdd(&pool[cg * O_DIM + 2 * lane], a.x);
        atomicAdd(&pool[cg * O_DIM + 2 * lane + 1], a.y);
    }
}

__global__ void k_final(const float* __restrict__ pool, const float* __restrict__ cnt,
                        float* __restrict__ out) {
    int t = blockIdx.x * blockDim.x + threadIdx.x;
    if (t < N_GRAPH * O_DIM) {
        int g = t / O_DIM;
        out[t] = pool[t] / fmaxf(cnt[g], 1.0f);
    }
}

// ---------------- launch ----------------

extern "C" void kernel_launch(void* const* d_in, const int* in_sizes, int n_in,
                              void* d_out, int out_size, void* d_ws, size_t ws_size,
                              hipStream_t stream) {
    const float* cf   = (const float*)d_in[0];   // [V,128]
    const float* W1   = (const float*)d_in[1];   // [128,256]
    const float* b1   = (const float*)d_in[2];   // [256]
    const float* W2   = (const float*)d_in[3];   // [256,128]
    const float* b2   = (const float*)d_in[4];   // [128]
    const float* ew   = (const float*)d_in[5];   // [E]
    const int*   nidx = (const int*)d_in[6];     // [N]
    const int*   eidx = (const int*)d_in[7];     // [2,E]
    const int*   bidx = (const int*)d_in[8];     // [N]
    float* out = (float*)d_out;

    const int* row = eidx;            // source
    const int* col = eidx + N_EDGES;  // target

    // workspace layout (bytes)
    char* ws = (char*)d_ws;
    size_t off = 0;
    int*   hist  = (int*)  (ws + off); off += (size_t)N_NODES * 4;          // 256K
    int*   hoffs = (int*)  (ws + off); off += (size_t)N_NODES * 4;          // 256K
    int*   bsum  = (int*)  (ws + off); off += 4096;
    float* dis   = (float*)(ws + off); off += (size_t)N_NODES * 4;          // 256K
    int*   offs  = (int*)  (ws + off); off += (size_t)(N_NODES + 16) * 4;   // 256K
    int2*  csr   = (int2*) (ws + off); off += (size_t)N_EDGES * 8;          // 16M
    float* pool  = (float*)(ws + off); off += (size_t)(N_GRAPH * O_DIM + N_GRAPH) * 4;
    __half* cf16 = (__half*)(ws + off); off += (size_t)V_SIZE * F_IN * 2;   // 256K
    off = (off + 255) & ~(size_t)255;
    float* aggX  = (float*)(ws + off); off += (size_t)N_NODES * F_IN * 4;   // 32M
    float* h1    = (float*)(ws + off);                                      // 64M
    int4*  part  = (int4*)aggX;      // 32M bucket buffer, dead before k_agg0
    __half* xw2h = (__half*)aggX;    // aggX dead after gemm1
    float* cntf  = pool + N_GRAPH * O_DIM;

    // 1. init + bucket histogram + scan; graph counts via binary search
    k_init<<<N_NODES / 256, 256, 0, stream>>>(pool, cf, cf16);
    k_gcount<<<1, 256, 0, stream>>>(bidx, cntf);
    k_hist<<<NBLK, 256, 0, stream>>>(col, hist);
    k_scan1<<<256, 256, 0, stream>>>(hist, hoffs, bsum);
    k_scan2<<<1, 256, 0, stream>>>(bsum);
    k_scan3<<<256, 256, 0, stream>>>(hoffs, bsum);

    // 2. partition -> per-bucket build (deg/dis/offs/CSR) -> nrm transform
    k_part<<<NBLK, 256, 0, stream>>>(row, col, ew, nidx, hoffs, part);
    k_build<<<256, 256, 0, stream>>>(hoffs, part, csr, dis, offs);
    k_nrm<<<N_EDGES / 256, 256, 0, stream>>>(csr, dis);

    // 3. layer 1: aggregate fp16 features (wave/node), then GEMM (+b1, relu)
    k_agg0<<<N_NODES / 4, 256, 0, stream>>>((const __half2*)cf16, nidx, dis, offs, csr,
                                            (float2*)aggX);
    k_gemm1<<<N_NODES / 32, 256, 0, stream>>>(aggX, W1, b1, h1);

    // 4. layer 2: GEMM -> fp16, aggregate + relu + LDS-reduced pool
    k_gemm2<<<N_NODES / 32, 256, 0, stream>>>(h1, W2, xw2h);
    k_agg2_pool<<<N_NODES / 4, 256, 0, stream>>>((const __half2*)xw2h, b2, dis, offs, csr,
                                                 bidx, pool);

    // 5. final divide
    k_final<<<(N_GRAPH * O_DIM + 255) / 256, 256, 0, stream>>>(pool, cntf, out);
}